// Round 4
// baseline (1254.654 us; speedup 1.0000x reference)
//
#include <hip/hip_runtime.h>
#include <math.h>

// Problem constants
#define T_STEPS 256
#define BATCH   256
#define HID     512
#define DIN     640     // P*F = 5*128
#define NCOL    2048    // 4*H
#define NCLASS  60
#define KSTEPS  36      // 1152 / 32
#define KX      20      // x-part k-steps (640/32)
#define KH      16      // h-part k-steps (512/32)

typedef float f32x4 __attribute__((ext_vector_type(4)));
typedef short s16x8 __attribute__((ext_vector_type(8)));

// ws layout (bytes):
//   [0,        4096)      control: safecnt[8*32] ints @0, groupflags[8*32] ints @1024,
//                         precnt @2048, xccbuf[256] ints @2176
//   [4096,     4722688)   Wf  bf16 packed weights (128*36*64*8 shorts)
//   [4722688,  4984832)   hb0 bf16 h frag buffer (256 KB)
//   [4984832,  5246976)   hb1 bf16 h frag buffer
//   [5246976,  5771264)   hplain fp32 (256x512)
//   [5771264,  89657344)  xf  bf16 x A-frags [t][mbg][ks][lane][8] (84 MB)
#define WF_OFF   4096
#define HB0_OFF  4722688
#define HB1_OFF  4984832
#define HPL_OFF  5246976
#define XF_OFF   5771264
#define WS_NEED  89657344ULL

__device__ __forceinline__ unsigned short f2bf(float x) {
    union { float f; unsigned u; } v; v.f = x;
    unsigned r = v.u + 0x7fffu + ((v.u >> 16) & 1u);   // round-to-nearest-even
    return (unsigned short)(r >> 16);
}

__device__ __forceinline__ s16x8 pack8(float4 a, float4 b) {
    s16x8 r;
    r[0] = (short)f2bf(a.x); r[1] = (short)f2bf(a.y);
    r[2] = (short)f2bf(a.z); r[3] = (short)f2bf(a.w);
    r[4] = (short)f2bf(b.x); r[5] = (short)f2bf(b.y);
    r[6] = (short)f2bf(b.z); r[7] = (short)f2bf(b.w);
    return r;
}

// Fast-math activations (exact formulas; only v_exp/v_rcp rounding differs
// from libm — far below the bf16 h-exchange quantization already present).
__device__ __forceinline__ float fsigmoid(float x) {
    return __builtin_amdgcn_rcpf(1.f + __expf(-x));
}
__device__ __forceinline__ float ftanh_f(float x) {
    float e = __expf(-2.f * fabsf(x));
    float r = (1.f - e) * __builtin_amdgcn_rcpf(1.f + e);
    return copysignf(r, x);
}

// ---------------------------------------------------------------------------
// Pack [Wx; Wh] (1152 x 2048 fp32) into bf16 B-fragment-linear layout.
// ---------------------------------------------------------------------------
__global__ __launch_bounds__(256) void pack_w_kernel(
    const float* __restrict__ Wx, const float* __restrict__ Wh,
    unsigned short* __restrict__ Wf)
{
    int g = blockIdx.x * 256 + threadIdx.x;      // [0, 128*36*64)
    int nb  = g / (KSTEPS * 64);
    int rem = g - nb * (KSTEPS * 64);
    int ks = rem >> 6;
    int lane = rem & 63;
    int gate = nb & 3, hg = nb >> 2;
    int n = gate * 512 + hg * 16 + (lane & 15);
    int kbase = ks * 32 + (lane >> 4) * 8;
    s16x8 frag;
    #pragma unroll
    for (int j = 0; j < 8; j++) {
        int k = kbase + j;
        float v = (k < DIN) ? Wx[(size_t)k * NCOL + n]
                            : Wh[(size_t)(k - DIN) * NCOL + n];
        frag[j] = (short)f2bf(v);
    }
    *(s16x8*)(Wf + (size_t)g * 8) = frag;
}

// ---------------------------------------------------------------------------
// Pre-convert x to bf16 A-fragment layout: xf[((t*16+mbg)*20+ks)*64+lane][8]
// ---------------------------------------------------------------------------
__global__ __launch_bounds__(256) void xf_kernel(
    const float* __restrict__ x, unsigned short* __restrict__ xf)
{
    int bid = blockIdx.x;            // t*16 + mbg
    int t = bid >> 4, mbg = bid & 15;
    for (int it = threadIdx.x; it < 1280; it += 256) {
        int ks = it >> 6, lane = it & 63;
        int row = mbg * 16 + (lane & 15);
        int k = ks * 32 + (lane >> 4) * 8;
        int p = k >> 7, f = k & 127;
        const float* sp = x + ((size_t)(row * 5 + p) * 256 + t) * 128 + f;
        float4 u0 = *(const float4*)sp;
        float4 u1 = *(const float4*)(sp + 4);
        s16x8 o = pack8(u0, u1);
        *(s16x8*)(xf + ((size_t)bid * 1280 + it) * 8) = o;
    }
}

// ---------------------------------------------------------------------------
// Persistent phased-LSTM. 256 WGs x 256 thr, 1 WG/CU. WG=(mt=bid&7, hg=bid>>3).
// FAST protocol (group XCD-uniform, verified via HW_REG_XCC_ID):
//   h exchange: plain write-through stores -> XCD L2; buffer_inv + plain
//     coalesced loads (R0-proven). The poll loop's final buffer_inv doubles
//     as the pre-h-load invalidate (no loads touch h lines in between).
//   barrier ARRIVE: per-WG flag word, plain store AFTER the vmcnt-draining
//     __syncthreads (same visibility mechanism as the h publish itself).
//   barrier WAIT: ALL FOUR waves poll independently (buffer_inv + one
//     coalesced 32-flag load + ballot) — no post-poll __syncthreads, no
//     barrier-release latency, each wave starts its h loads immediately.
//     LDS gl hazard remains covered by the dump-sync and publish-sync.
// xf A-frags double-buffered in registers: loads for step t+1 issue at the
//   TOP of step t (before the x-MFMAs), so they have the whole step to fly
//   and every __syncthreads drain waits ~zero residual.
// SAFE (fallback, proven): relaxed agent-scope atomics at LLC + tid0 poll
//   + full __syncthreads structure.
// ---------------------------------------------------------------------------
#define PLSTM_STEP(T, CUR, NXT)                                               \
  {                                                                           \
    /* prefetch xf for T+1 into NXT (clamped; garbage unused at T=255) */     \
    int tp_ = ((T) < T_STEPS - 1) ? (T) + 1 : (T);                            \
    const s16x8* xn_ = (const s16x8*)xf + ((size_t)tp_ * 16 + mbg) * KX * 64; \
    _Pragma("unroll")                                                         \
    for (int ks = 0; ks < KX; ks++) NXT[ks] = xn_[ks * 64 + lane];            \
    /* x phase */                                                             \
    f32x4 acc0 = {0.f, 0.f, 0.f, 0.f}, acc1 = acc0;                           \
    _Pragma("unroll")                                                         \
    for (int ks = 0; ks < KX; ks++) {                                         \
      s16x8 b0 = *(const s16x8*)(wfl + (((n0    ) * KSTEPS + ks) * 64 + lane) * 8); \
      s16x8 b1 = *(const s16x8*)(wfl + (((n0 + 1) * KSTEPS + ks) * 64 + lane) * 8); \
      acc0 = __builtin_amdgcn_mfma_f32_16x16x32_bf16(CUR[ks], b0, acc0, 0, 0, 0);   \
      acc1 = __builtin_amdgcn_mfma_f32_16x16x32_bf16(CUR[ks], b1, acc1, 0, 0, 0);   \
    }                                                                         \
    /* group barrier wait */                                                  \
    if (fast) {                                                               \
      for (;;) {                                                              \
        asm volatile("buffer_inv" ::: "memory");    /* drop CU L1 */          \
        int v_ = (T);                                                         \
        if (lane < 32) v_ = *(volatile int*)(flg + lane);                     \
        if (__ballot(v_ >= (T)) == ~0ull) break;                              \
      }                                                                       \
    } else {                                                                  \
      if (tid == 0) {                                                         \
        while (__hip_atomic_load(scnt, __ATOMIC_RELAXED,                      \
                                 __HIP_MEMORY_SCOPE_AGENT) < 32 * (T))        \
          __builtin_amdgcn_s_sleep(1);                                        \
      }                                                                       \
      __syncthreads();                                                        \
    }                                                                         \
    const unsigned short* hsrc = ((T) & 1) ? hb1 : hb0;                       \
    unsigned short*       hdst = ((T) & 1) ? hb0 : hb1;                       \
    /* h phase */                                                             \
    if (fast) {                                                               \
      const s16x8* hs_ = (const s16x8*)hsrc + (size_t)mbg * KH * 64;          \
      _Pragma("unroll")                                                       \
      for (int khs = 0; khs < KH; khs++) {                                    \
        s16x8 a_ = hs_[khs * 64 + lane];                                      \
        int ks = KX + khs;                                                    \
        s16x8 b0 = *(const s16x8*)(wfl + (((n0    ) * KSTEPS + ks) * 64 + lane) * 8); \
        s16x8 b1 = *(const s16x8*)(wfl + (((n0 + 1) * KSTEPS + ks) * 64 + lane) * 8); \
        acc0 = __builtin_amdgcn_mfma_f32_16x16x32_bf16(a_, b0, acc0, 0, 0, 0);\
        acc1 = __builtin_amdgcn_mfma_f32_16x16x32_bf16(a_, b1, acc1, 0, 0, 0);\
      }                                                                       \
    } else {                                                                  \
      const unsigned long long* hq_ =                                         \
          (const unsigned long long*)(hsrc + ((size_t)mbg * KH * 64) * 8);    \
      _Pragma("unroll")                                                       \
      for (int khs = 0; khs < KH; khs++) {                                    \
        union { unsigned long long q[2]; s16x8 v; } a_;                       \
        size_t base_ = ((size_t)khs * 64 + lane) * 2;                         \
        a_.q[0] = __hip_atomic_load(hq_ + base_,     __ATOMIC_RELAXED,        \
                                    __HIP_MEMORY_SCOPE_AGENT);                \
        a_.q[1] = __hip_atomic_load(hq_ + base_ + 1, __ATOMIC_RELAXED,        \
                                    __HIP_MEMORY_SCOPE_AGENT);                \
        int ks = KX + khs;                                                    \
        s16x8 b0 = *(const s16x8*)(wfl + (((n0    ) * KSTEPS + ks) * 64 + lane) * 8); \
        s16x8 b1 = *(const s16x8*)(wfl + (((n0 + 1) * KSTEPS + ks) * 64 + lane) * 8); \
        acc0 = __builtin_amdgcn_mfma_f32_16x16x32_bf16(a_.v, b0, acc0, 0, 0, 0);      \
        acc1 = __builtin_amdgcn_mfma_f32_16x16x32_bf16(a_.v, b1, acc1, 0, 0, 0);      \
      }                                                                       \
    }                                                                         \
    /* dump accs to LDS (C/D: col=lane&15, row=quad*4+reg) */                 \
    {                                                                         \
      int colb_ = n0 * 16 + l16;                                              \
      int rowb_ = mb * 16 + quad * 4;                                         \
      _Pragma("unroll")                                                       \
      for (int r = 0; r < 4; r++) {                                           \
        gl[rowb_ + r][colb_]      = acc0[r];                                  \
        gl[rowb_ + r][colb_ + 16] = acc1[r];                                  \
      }                                                                       \
    }                                                                         \
    __syncthreads();                                                          \
    /* epilogue */                                                            \
    float hn2_[2];                                                            \
    _Pragma("unroll")                                                         \
    for (int r = 0; r < 2; r++) {                                             \
      int j_l = j0 + r;                                                       \
      float iv = fsigmoid(gl[b_l][j_l]      + bi[r]);                         \
      float fv = fsigmoid(gl[b_l][16 + j_l] + bff[r]);                        \
      float gv = ftanh_f (gl[b_l][32 + j_l] + bg[r]);                         \
      float ov = fsigmoid(gl[b_l][48 + j_l] + bo[r]);                         \
      float ct = fv * creg[r] + iv * gv;                                      \
      float ht = ov * ftanh_f(ct);                                            \
      float ph = phs[r];                                                      \
      float kg = (ph < 0.025f) ? 40.f * ph                                    \
               : ((ph < 0.05f) ? 2.f - 40.f * ph : 0.001f * ph);              \
      creg[r] = kg * ct + (1.f - kg) * creg[r];                               \
      hreg[r] = kg * ht + (1.f - kg) * hreg[r];                               \
      hn2_[r] = hreg[r];                                                      \
      ph += itau[r];                                                          \
      phs[r] = (ph >= 1.f) ? ph - 1.f : ph;                                   \
    }                                                                         \
    unsigned pv_ = (unsigned)f2bf(hn2_[0]) | ((unsigned)f2bf(hn2_[1]) << 16); \
    if (fast) {                                                               \
      ((unsigned*)hdst)[pub32] = pv_;            /* write-through to L2 */    \
    } else {                                                                  \
      __hip_atomic_store((unsigned*)hdst + pub32, pv_, __ATOMIC_RELAXED,      \
                         __HIP_MEMORY_SCOPE_AGENT);                           \
    }                                                                         \
    if ((T) == T_STEPS - 1) {                                                 \
      hplain[(size_t)bG * HID + jG0]     = hn2_[0];                           \
      hplain[(size_t)bG * HID + jG0 + 1] = hn2_[1];                           \
    }                                                                         \
    __syncthreads();   /* drains vmcnt: publish at coherence point (xf        \
                          prefetch loads issued a whole step ago: ~done) */   \
    /* group barrier arrive */                                                \
    if (tid == 0) {                                                           \
      if (fast) {                                                             \
        *(volatile int*)(flg + hg) = (T) + 1;    /* plain flag store -> L2 */ \
      } else {                                                                \
        __hip_atomic_fetch_add(scnt, 1, __ATOMIC_RELAXED,                     \
                               __HIP_MEMORY_SCOPE_AGENT);                     \
      }                                                                       \
    }                                                                         \
  }

__global__ __launch_bounds__(256, 1) void plstm_persist3(
    const unsigned short* __restrict__ xf,
    const unsigned short* __restrict__ Wf,
    unsigned short* __restrict__ hb0,
    unsigned short* __restrict__ hb1,
    float* __restrict__ hplain,
    const float* __restrict__ bias,
    const float* __restrict__ tau,
    const float* __restrict__ shift,
    int* __restrict__ ctl)
{
    __shared__ unsigned short wfl[4 * KSTEPS * 64 * 8];  // 147456 B
    __shared__ float gl[32][65];                          // 8320 B
    __shared__ int protflag;

    int tid = threadIdx.x;
    int lane = tid & 63, w = tid >> 6;
    int bid = blockIdx.x;
    int mt = bid & 7, hg = bid >> 3;
    int quad = lane >> 4, l16 = lane & 15;
    int mb = w & 1;
    int n0 = (w >> 1) * 2;

    // --- XCD-uniformity handshake (one-time) ---
    int xcc = __builtin_amdgcn_s_getreg((31 << 11) | (0 << 6) | 20); // HW_REG_XCC_ID
    if (tid == 0) {
        __hip_atomic_store(&ctl[544 + bid], xcc + 1, __ATOMIC_RELAXED,
                           __HIP_MEMORY_SCOPE_AGENT);
        asm volatile("s_waitcnt vmcnt(0)" ::: "memory");
        __hip_atomic_fetch_add(&ctl[512], 1, __ATOMIC_RELAXED,
                               __HIP_MEMORY_SCOPE_AGENT);
        while (__hip_atomic_load(&ctl[512], __ATOMIC_RELAXED,
                                 __HIP_MEMORY_SCOPE_AGENT) < 256)
            __builtin_amdgcn_s_sleep(1);
    }

    // --- stage weight slice into LDS (overlaps handshake) ---
    {
        const s16x8* src = (const s16x8*)(Wf + (size_t)(hg * 4) * KSTEPS * 64 * 8);
        s16x8* dst = (s16x8*)wfl;
        #pragma unroll
        for (int i = 0; i < 36; i++)
            dst[i * 256 + tid] = src[i * 256 + tid];
    }
    __syncthreads();

    if (w == 0) {
        int pred = 1;
        if (lane < 32) {
            int v = __hip_atomic_load(&ctl[544 + mt + 8 * lane], __ATOMIC_RELAXED,
                                      __HIP_MEMORY_SCOPE_AGENT);
            pred = (v == xcc + 1);
        }
        unsigned long long bal = __ballot(pred);
        if (lane == 0) protflag = (bal == ~0ull) ? 1 : 0;
    }
    __syncthreads();
    int fast = protflag;

    // --- per-thread epilogue constants + register state (2 cells) ---
    int b_l = tid >> 3;
    int j0  = (tid & 7) * 2;
    int bG  = mt * 32 + b_l;
    int jG0 = hg * 16 + j0;
    float bi[2], bff[2], bg[2], bo[2], phs[2], itau[2];
    #pragma unroll
    for (int r = 0; r < 2; r++) {
        int jG = jG0 + r;
        bi[r] = bias[jG];        bff[r] = bias[512 + jG];
        bg[r] = bias[1024 + jG]; bo[r] = bias[1536 + jG];
        float tj = tau[jG], sj = shift[jG];
        itau[r] = 1.f / tj;                      // precise divide, once
        float ph = fmodf(-sj, tj);
        ph = (ph < 0.f) ? ph + tj : ph;
        phs[r] = ph * itau[r];                   // phi at t=0; advanced by itau/step
    }
    float creg[2] = {0.f, 0.f}, hreg[2] = {0.f, 0.f};
    size_t pub32;
    {
        int mb2 = bG >> 4, khs2 = jG0 >> 5;
        int ln  = (bG & 15) + ((jG0 >> 3) & 3) * 16;
        pub32 = ((((size_t)mb2 * KH + khs2) * 64 + ln) * 8 + (jG0 & 7)) >> 1;
    }

    int mbg = mt * 2 + mb;
    int* flg  = &ctl[256 + mt * 32];   // fast-mode per-WG flags (32 ints / group)
    int* scnt = &ctl[mt * 32];         // safe-mode counter

    // --- double-buffered xf A-frag registers; preload t=0 into bank A ---
    s16x8 xaA[KX], xaB[KX];
    {
        const s16x8* x0 = (const s16x8*)xf + (size_t)mbg * KX * 64;
        #pragma unroll
        for (int ks = 0; ks < KX; ks++) xaA[ks] = x0[ks * 64 + lane];
    }

    for (int tt = 0; tt < T_STEPS; tt += 2) {
        PLSTM_STEP(tt,     xaA, xaB)
        PLSTM_STEP(tt + 1, xaB, xaA)
    }
}

// ---------------------------------------------------------------------------
// FALLBACK persistent kernel (proven) — used when ws_size < WS_NEED.
// ---------------------------------------------------------------------------
__global__ __launch_bounds__(256, 1) void plstm_persist(
    const float* __restrict__ x,
    const unsigned short* __restrict__ Wf,
    unsigned short* __restrict__ hb0,
    unsigned short* __restrict__ hb1,
    float* __restrict__ hplain,
    const float* __restrict__ bias,
    const float* __restrict__ tau,
    const float* __restrict__ shift,
    int* __restrict__ cnt)
{
    __shared__ unsigned short wfl[4 * KSTEPS * 64 * 8];
    __shared__ float gl[32][65];

    int tid = threadIdx.x;
    int lane = tid & 63, w = tid >> 6;
    int mt = blockIdx.x & 7, hg = blockIdx.x >> 3;
    int quad = lane >> 4, l16 = lane & 15;
    int mb = w & 1;
    int n0 = (w >> 1) * 2;

    {
        const s16x8* src = (const s16x8*)(Wf + (size_t)(hg * 4) * KSTEPS * 64 * 8);
        s16x8* dst = (s16x8*)wfl;
        #pragma unroll
        for (int i = 0; i < 36; i++)
            dst[i * 256 + tid] = src[i * 256 + tid];
    }

    int b_l  = tid >> 3;
    int j_l0 = (tid & 7) * 2;
    int bG   = mt * 32 + b_l;
    int jG0  = hg * 16 + j_l0;
    float bi[2], bff[2], bg[2], bo[2], tj[2], sj[2];
    #pragma unroll
    for (int r = 0; r < 2; r++) {
        int jG = jG0 + r;
        bi[r] = bias[jG];        bff[r] = bias[512 + jG];
        bg[r] = bias[1024 + jG]; bo[r] = bias[1536 + jG];
        tj[r] = tau[jG];         sj[r] = shift[jG];
    }
    float creg[2] = {0.f, 0.f}, hreg[2] = {0.f, 0.f};
    size_t pub32;
    {
        int mb2  = bG >> 4, khs2 = jG0 >> 5;
        int ln   = (bG & 15) + ((jG0 >> 3) & 3) * 16;
        pub32 = ((((size_t)mb2 * KH + khs2) * 64 + ln) * 8 + (jG0 & 7)) >> 1;
    }
    __syncthreads();

    int rowA = mt * 32 + mb * 16 + l16;
    int mbg  = mt * 2 + mb;
    int* mycnt = cnt + mt * 32;

    for (int t = 0; t < T_STEPS; t++) {
        f32x4 acc0 = {0.f,0.f,0.f,0.f}, acc1 = acc0;
        #pragma unroll
        for (int ks = 0; ks < KX; ks++) {
            int k = ks * 32 + quad * 8;
            int p = k >> 7, f = k & 127;
            const float* sp = x + ((size_t)(rowA * 5 + p) * 256 + t) * 128 + f;
            float4 u0 = *(const float4*)sp;
            float4 u1 = *(const float4*)(sp + 4);
            s16x8 a = pack8(u0, u1);
            s16x8 b0 = *(const s16x8*)(wfl + (((n0    ) * KSTEPS + ks) * 64 + lane) * 8);
            s16x8 b1 = *(const s16x8*)(wfl + (((n0 + 1) * KSTEPS + ks) * 64 + lane) * 8);
            acc0 = __builtin_amdgcn_mfma_f32_16x16x32_bf16(a, b0, acc0, 0, 0, 0);
            acc1 = __builtin_amdgcn_mfma_f32_16x16x32_bf16(a, b1, acc1, 0, 0, 0);
        }

        if (tid == 0) {
            while (__hip_atomic_load(mycnt, __ATOMIC_RELAXED,
                                     __HIP_MEMORY_SCOPE_AGENT) < 32 * t)
                __builtin_amdgcn_s_sleep(1);
        }
        __syncthreads();

        const unsigned short* hsrc = (t & 1) ? hb1 : hb0;
        unsigned short*       hdst = (t & 1) ? hb0 : hb1;

        const unsigned long long* hq =
            (const unsigned long long*)(hsrc + ((size_t)mbg * KH * 64) * 8);
        #pragma unroll
        for (int khs = 0; khs < KH; khs++) {
            union { unsigned long long q[2]; s16x8 v; } a;
            size_t base = ((size_t)khs * 64 + lane) * 2;
            a.q[0] = __hip_atomic_load(hq + base,     __ATOMIC_RELAXED,
                                       __HIP_MEMORY_SCOPE_AGENT);
            a.q[1] = __hip_atomic_load(hq + base + 1, __ATOMIC_RELAXED,
                                       __HIP_MEMORY_SCOPE_AGENT);
            int ks = KX + khs;
            s16x8 b0 = *(const s16x8*)(wfl + (((n0    ) * KSTEPS + ks) * 64 + lane) * 8);
            s16x8 b1 = *(const s16x8*)(wfl + (((n0 + 1) * KSTEPS + ks) * 64 + lane) * 8);
            acc0 = __builtin_amdgcn_mfma_f32_16x16x32_bf16(a.v, b0, acc0, 0, 0, 0);
            acc1 = __builtin_amdgcn_mfma_f32_16x16x32_bf16(a.v, b1, acc1, 0, 0, 0);
        }

        int colb = n0 * 16 + l16;
        int rowb = mb * 16 + quad * 4;
        #pragma unroll
        for (int r = 0; r < 4; r++) {
            gl[rowb + r][colb]      = acc0[r];
            gl[rowb + r][colb + 16] = acc1[r];
        }
        __syncthreads();

        float hn2[2];
        #pragma unroll
        for (int r = 0; r < 2; r++) {
            int j_l = j_l0 + r;
            float iv = gl[b_l][j_l]      + bi[r];
            float fv = gl[b_l][16 + j_l] + bff[r];
            float gv = gl[b_l][32 + j_l] + bg[r];
            float ov = gl[b_l][48 + j_l] + bo[r];
            iv = 1.f / (1.f + expf(-iv));
            fv = 1.f / (1.f + expf(-fv));
            gv = tanhf(gv);
            ov = 1.f / (1.f + expf(-ov));
            float ct = fv * creg[r] + iv * gv;
            float ht = ov * tanhf(ct);
            float phi = fmodf((float)t - sj[r], tj[r]);
            phi = (phi < 0.f) ? phi + tj[r] : phi;
            phi /= tj[r];
            float kg = (phi < 0.025f) ? 40.f * phi
                     : ((phi < 0.05f) ? 2.f - 40.f * phi : 0.001f * phi);
            creg[r] = kg * ct + (1.f - kg) * creg[r];
            hreg[r] = kg * ht + (1.f - kg) * hreg[r];
            hn2[r] = hreg[r];
        }
        unsigned pv = (unsigned)f2bf(hn2[0]) | ((unsigned)f2bf(hn2[1]) << 16);
        __hip_atomic_store((unsigned*)hdst + pub32, pv, __ATOMIC_RELAXED,
                           __HIP_MEMORY_SCOPE_AGENT);
        if (t == T_STEPS - 1) {
            hplain[(size_t)bG * HID + jG0]     = hn2[0];
            hplain[(size_t)bG * HID + jG0 + 1] = hn2[1];
        }
        __syncthreads();

        if (tid == 0)
            __hip_atomic_fetch_add(mycnt, 1, __ATOMIC_RELAXED,
                                   __HIP_MEMORY_SCOPE_AGENT);
    }
}

// ---------------------------------------------------------------------------
// Final FC (512 -> 60) + log_softmax. One wave per batch row.
// ---------------------------------------------------------------------------
__global__ __launch_bounds__(64) void fc_kernel(
    const float* __restrict__ hplain, const float* __restrict__ fcw,
    const float* __restrict__ fcb, float* __restrict__ out)
{
    int b = blockIdx.x, lane = threadIdx.x;
    float logit = -INFINITY;
    if (lane < NCLASS) {
        float s = fcb[lane];
        const float* hp = hplain + (size_t)b * HID;
        #pragma unroll 8
        for (int k = 0; k < HID; k++)
            s += hp[k] * fcw[(size_t)k * NCLASS + lane];
        logit = s;
    }
    float m = logit;
    for (int off = 32; off > 0; off >>= 1)
        m = fmaxf(m, __shfl_xor(m, off, 64));
    float e = (lane < NCLASS) ? expf(logit - m) : 0.f;
    float se = e;
    for (int off = 32; off > 0; off >>= 1)
        se += __shfl_xor(se, off, 64);
    if (lane < NCLASS)
        out[(size_t)b * NCLASS + lane] = logit - m - logf(se);
}

extern "C" void kernel_launch(void* const* d_in, const int* in_sizes, int n_in,
                              void* d_out, int out_size, void* d_ws, size_t ws_size,
                              hipStream_t stream)
{
    const float* x     = (const float*)d_in[0];
    const float* Wx    = (const float*)d_in[1];
    const float* Wh    = (const float*)d_in[2];
    const float* bias  = (const float*)d_in[3];
    const float* tau   = (const float*)d_in[4];
    const float* shift = (const float*)d_in[5];
    const float* fcw   = (const float*)d_in[6];
    const float* fcb   = (const float*)d_in[7];
    float* out = (float*)d_out;
    char* ws = (char*)d_ws;

    int*            ctl    = (int*)ws;
    unsigned short* Wf     = (unsigned short*)(ws + WF_OFF);
    unsigned short* hb0    = (unsigned short*)(ws + HB0_OFF);
    unsigned short* hb1    = (unsigned short*)(ws + HB1_OFF);
    float*          hplain = (float*)(ws + HPL_OFF);
    unsigned short* xfb    = (unsigned short*)(ws + XF_OFF);

    hipMemsetAsync(ws, 0, 4096, stream);                 // control block
    hipMemsetAsync(ws + HB0_OFF, 0, 262144, stream);     // h0 = 0

    pack_w_kernel<<<dim3(1152), dim3(256), 0, stream>>>(Wx, Wh, Wf);

    if (ws_size >= WS_NEED) {
        xf_kernel<<<dim3(4096), dim3(256), 0, stream>>>(x, xfb);
        plstm_persist3<<<dim3(256), dim3(256), 0, stream>>>(
            xfb, Wf, hb0, hb1, hplain, bias, tau, shift, ctl);
    } else {
        plstm_persist<<<dim3(256), dim3(256), 0, stream>>>(
            x, Wf, hb0, hb1, hplain, bias, tau, shift, ctl);
    }

    fc_kernel<<<dim3(256), dim3(64), 0, stream>>>(hplain, fcw, fcb, out);
}

// Round 5
// 1105.035 us; speedup vs baseline: 1.1354x; 1.1354x over previous
//
#include <hip/hip_runtime.h>
#include <math.h>

// Problem constants
#define T_STEPS 256
#define BATCH   256
#define HID     512
#define DIN     640     // P*F = 5*128
#define NCOL    2048    // 4*H
#define NCLASS  60
#define KSTEPS  36      // 1152 / 32
#define KX      20      // x-part k-steps (640/32)
#define KH      16      // h-part k-steps (512/32)

typedef float f32x4 __attribute__((ext_vector_type(4)));
typedef short s16x8 __attribute__((ext_vector_type(8)));

// ws layout (bytes):
//   [0,        4096)      control: safecnt[8*32] ints @0, groupflags[8*32] ints @1024,
//                         precnt @2048, xccbuf[256] ints @2176
//   [4096,     4722688)   Wf  bf16 packed weights (128*36*64*8 shorts)
//   [4722688,  4984832)   hb0 bf16 h frag buffer (256 KB)
//   [4984832,  5246976)   hb1 bf16 h frag buffer
//   [5246976,  5771264)   hplain fp32 (256x512)
//   [5771264,  89657344)  xf  bf16 x A-frags [t][mbg][ks][lane][8] (84 MB)
#define WF_OFF   4096
#define HB0_OFF  4722688
#define HB1_OFF  4984832
#define HPL_OFF  5246976
#define XF_OFF   5771264
#define WS_NEED  89657344ULL

__device__ __forceinline__ unsigned short f2bf(float x) {
    union { float f; unsigned u; } v; v.f = x;
    unsigned r = v.u + 0x7fffu + ((v.u >> 16) & 1u);   // round-to-nearest-even
    return (unsigned short)(r >> 16);
}

__device__ __forceinline__ s16x8 pack8(float4 a, float4 b) {
    s16x8 r;
    r[0] = (short)f2bf(a.x); r[1] = (short)f2bf(a.y);
    r[2] = (short)f2bf(a.z); r[3] = (short)f2bf(a.w);
    r[4] = (short)f2bf(b.x); r[5] = (short)f2bf(b.y);
    r[6] = (short)f2bf(b.z); r[7] = (short)f2bf(b.w);
    return r;
}

// Fast-math activations. Mathematically exact formulas; only v_exp/v_rcp
// rounding (~1e-7 rel) differs from libm — far below the bf16 h-exchange
// quantization already present.
__device__ __forceinline__ float fsigmoid(float x) {
    return __builtin_amdgcn_rcpf(1.f + __expf(-x));
}
__device__ __forceinline__ float ftanh_f(float x) {
    float e = __expf(-2.f * fabsf(x));
    float r = (1.f - e) * __builtin_amdgcn_rcpf(1.f + e);
    return copysignf(r, x);
}

// ---------------------------------------------------------------------------
// Pack [Wx; Wh] (1152 x 2048 fp32) into bf16 B-fragment-linear layout.
// ---------------------------------------------------------------------------
__global__ __launch_bounds__(256) void pack_w_kernel(
    const float* __restrict__ Wx, const float* __restrict__ Wh,
    unsigned short* __restrict__ Wf)
{
    int g = blockIdx.x * 256 + threadIdx.x;      // [0, 128*36*64)
    int nb  = g / (KSTEPS * 64);
    int rem = g - nb * (KSTEPS * 64);
    int ks = rem >> 6;
    int lane = rem & 63;
    int gate = nb & 3, hg = nb >> 2;
    int n = gate * 512 + hg * 16 + (lane & 15);
    int kbase = ks * 32 + (lane >> 4) * 8;
    s16x8 frag;
    #pragma unroll
    for (int j = 0; j < 8; j++) {
        int k = kbase + j;
        float v = (k < DIN) ? Wx[(size_t)k * NCOL + n]
                            : Wh[(size_t)(k - DIN) * NCOL + n];
        frag[j] = (short)f2bf(v);
    }
    *(s16x8*)(Wf + (size_t)g * 8) = frag;
}

// ---------------------------------------------------------------------------
// Pre-convert x to bf16 A-fragment layout: xf[((t*16+mbg)*20+ks)*64+lane][8]
// ---------------------------------------------------------------------------
__global__ __launch_bounds__(256) void xf_kernel(
    const float* __restrict__ x, unsigned short* __restrict__ xf)
{
    int bid = blockIdx.x;            // t*16 + mbg
    int t = bid >> 4, mbg = bid & 15;
    for (int it = threadIdx.x; it < 1280; it += 256) {
        int ks = it >> 6, lane = it & 63;
        int row = mbg * 16 + (lane & 15);
        int k = ks * 32 + (lane >> 4) * 8;
        int p = k >> 7, f = k & 127;
        const float* sp = x + ((size_t)(row * 5 + p) * 256 + t) * 128 + f;
        float4 u0 = *(const float4*)sp;
        float4 u1 = *(const float4*)(sp + 4);
        s16x8 o = pack8(u0, u1);
        *(s16x8*)(xf + ((size_t)bid * 1280 + it) * 8) = o;
    }
}

// ---------------------------------------------------------------------------
// Persistent phased-LSTM. 256 WGs x 256 thr, 1 WG/CU. WG=(mt=bid&7, hg=bid>>3).
// Identical to the proven R2 structure EXCEPT the fast-path group barrier:
//   ARRIVE: plain per-WG flag store (flg[hg] = t+1) issued after the
//     vmcnt-draining __syncthreads — same write-through-to-L2 visibility
//     mechanism as the h publish itself. Removes the 32 serialized atomic
//     RMWs racing 32 pollers on a single L2 dword.
//   WAIT: wave 0 polls all 32 group flags: buffer_inv + ONE coalesced 128B
//     load + __ballot(flag >= t); then the existing __syncthreads releases
//     the workgroup (unchanged tid/wave structure vs R2).
// Everything else (xf register prefetch position, h phase, epilogue,
// publish) is byte-identical to the 780 µs R2 kernel.
// SAFE (fallback, proven): relaxed agent-scope atomics at LLC.
// ---------------------------------------------------------------------------
__global__ __launch_bounds__(256, 1) void plstm_persist3(
    const unsigned short* __restrict__ xf,
    const unsigned short* __restrict__ Wf,
    unsigned short* __restrict__ hb0,
    unsigned short* __restrict__ hb1,
    float* __restrict__ hplain,
    const float* __restrict__ bias,
    const float* __restrict__ tau,
    const float* __restrict__ shift,
    int* __restrict__ ctl)
{
    __shared__ unsigned short wfl[4 * KSTEPS * 64 * 8];  // 147456 B
    __shared__ float gl[32][65];                          // 8320 B
    __shared__ int protflag;

    int tid = threadIdx.x;
    int lane = tid & 63, w = tid >> 6;
    int bid = blockIdx.x;
    int mt = bid & 7, hg = bid >> 3;
    int quad = lane >> 4, l16 = lane & 15;
    int mb = w & 1;
    int n0 = (w >> 1) * 2;

    // --- XCD-uniformity handshake (one-time) ---
    int xcc = __builtin_amdgcn_s_getreg((31 << 11) | (0 << 6) | 20); // HW_REG_XCC_ID
    if (tid == 0) {
        __hip_atomic_store(&ctl[544 + bid], xcc + 1, __ATOMIC_RELAXED,
                           __HIP_MEMORY_SCOPE_AGENT);
        asm volatile("s_waitcnt vmcnt(0)" ::: "memory");
        __hip_atomic_fetch_add(&ctl[512], 1, __ATOMIC_RELAXED,
                               __HIP_MEMORY_SCOPE_AGENT);
        while (__hip_atomic_load(&ctl[512], __ATOMIC_RELAXED,
                                 __HIP_MEMORY_SCOPE_AGENT) < 256)
            __builtin_amdgcn_s_sleep(1);
    }

    // --- stage weight slice into LDS (overlaps handshake) ---
    {
        const s16x8* src = (const s16x8*)(Wf + (size_t)(hg * 4) * KSTEPS * 64 * 8);
        s16x8* dst = (s16x8*)wfl;
        #pragma unroll
        for (int i = 0; i < 36; i++)
            dst[i * 256 + tid] = src[i * 256 + tid];
    }
    __syncthreads();

    if (w == 0) {
        int pred = 1;
        if (lane < 32) {
            int v = __hip_atomic_load(&ctl[544 + mt + 8 * lane], __ATOMIC_RELAXED,
                                      __HIP_MEMORY_SCOPE_AGENT);
            pred = (v == xcc + 1);
        }
        unsigned long long bal = __ballot(pred);
        if (lane == 0) protflag = (bal == ~0ull) ? 1 : 0;
    }
    __syncthreads();
    int fast = protflag;

    // --- per-thread epilogue constants + register state (2 cells) ---
    int b_l = tid >> 3;
    int j0  = (tid & 7) * 2;
    int bG  = mt * 32 + b_l;
    int jG0 = hg * 16 + j0;
    float bi[2], bff[2], bg[2], bo[2], phs[2], itau[2];
    #pragma unroll
    for (int r = 0; r < 2; r++) {
        int jG = jG0 + r;
        bi[r] = bias[jG];        bff[r] = bias[512 + jG];
        bg[r] = bias[1024 + jG]; bo[r] = bias[1536 + jG];
        float tj = tau[jG], sj = shift[jG];
        itau[r] = 1.f / tj;                      // precise divide, once
        float ph = fmodf(-sj, tj);
        ph = (ph < 0.f) ? ph + tj : ph;
        phs[r] = ph * itau[r];                   // phi at t=0; advanced by itau/step
    }
    float creg[2] = {0.f, 0.f}, hreg[2] = {0.f, 0.f};
    size_t pub32;
    {
        int mb2 = bG >> 4, khs2 = jG0 >> 5;
        int ln  = (bG & 15) + ((jG0 >> 3) & 3) * 16;
        pub32 = ((((size_t)mb2 * KH + khs2) * 64 + ln) * 8 + (jG0 & 7)) >> 1;
    }

    int mbg = mt * 2 + mb;
    int* flg  = &ctl[256 + mt * 32];   // fast-mode per-WG flags (32 ints / group)
    int* scnt = &ctl[mt * 32];         // safe-mode counter

    // --- preload xf A-frags for t=0 into registers ---
    s16x8 xa[KX];
    {
        const s16x8* x0 = (const s16x8*)xf + (size_t)mbg * KX * 64;
        #pragma unroll
        for (int ks = 0; ks < KX; ks++) xa[ks] = x0[ks * 64 + lane];
    }

    for (int t = 0; t < T_STEPS; t++) {
        // ---- x phase: MFMA from register-prefetched A-frags ----
        f32x4 acc0 = {0.f, 0.f, 0.f, 0.f}, acc1 = acc0;
        #pragma unroll
        for (int ks = 0; ks < KX; ks++) {
            s16x8 b0 = *(const s16x8*)(wfl + (((n0    ) * KSTEPS + ks) * 64 + lane) * 8);
            s16x8 b1 = *(const s16x8*)(wfl + (((n0 + 1) * KSTEPS + ks) * 64 + lane) * 8);
            acc0 = __builtin_amdgcn_mfma_f32_16x16x32_bf16(xa[ks], b0, acc0, 0, 0, 0);
            acc1 = __builtin_amdgcn_mfma_f32_16x16x32_bf16(xa[ks], b1, acc1, 0, 0, 0);
        }

        // ---- group barrier wait ----
        if (fast) {
            if (w == 0) {
                for (;;) {
                    asm volatile("buffer_inv" ::: "memory");   // drop CU L1
                    int v = t;
                    if (lane < 32) v = *(volatile int*)(flg + lane); // 128B L2 read
                    if (__ballot(v >= t) == ~0ull) break;
                }
            }
        } else {
            if (tid == 0) {
                while (__hip_atomic_load(scnt, __ATOMIC_RELAXED,
                                         __HIP_MEMORY_SCOPE_AGENT) < 32 * t)
                    __builtin_amdgcn_s_sleep(1);
            }
        }
        __syncthreads();

        const unsigned short* hsrc = (t & 1) ? hb1 : hb0;
        unsigned short*       hdst = (t & 1) ? hb0 : hb1;

        // ---- h phase ----
        if (fast) {
            asm volatile("buffer_inv" ::: "memory");   // per-wave L1 invalidate
            const s16x8* hs = (const s16x8*)hsrc + (size_t)mbg * KH * 64;
            #pragma unroll
            for (int khs = 0; khs < KH; khs++) {
                s16x8 a  = hs[khs * 64 + lane];
                int ks = KX + khs;
                s16x8 b0 = *(const s16x8*)(wfl + (((n0    ) * KSTEPS + ks) * 64 + lane) * 8);
                s16x8 b1 = *(const s16x8*)(wfl + (((n0 + 1) * KSTEPS + ks) * 64 + lane) * 8);
                acc0 = __builtin_amdgcn_mfma_f32_16x16x32_bf16(a, b0, acc0, 0, 0, 0);
                acc1 = __builtin_amdgcn_mfma_f32_16x16x32_bf16(a, b1, acc1, 0, 0, 0);
            }
        } else {
            const unsigned long long* hq =
                (const unsigned long long*)(hsrc + ((size_t)mbg * KH * 64) * 8);
            #pragma unroll
            for (int khs = 0; khs < KH; khs++) {
                union { unsigned long long q[2]; s16x8 v; } a;
                size_t base = ((size_t)khs * 64 + lane) * 2;
                a.q[0] = __hip_atomic_load(hq + base,     __ATOMIC_RELAXED,
                                           __HIP_MEMORY_SCOPE_AGENT);
                a.q[1] = __hip_atomic_load(hq + base + 1, __ATOMIC_RELAXED,
                                           __HIP_MEMORY_SCOPE_AGENT);
                int ks = KX + khs;
                s16x8 b0 = *(const s16x8*)(wfl + (((n0    ) * KSTEPS + ks) * 64 + lane) * 8);
                s16x8 b1 = *(const s16x8*)(wfl + (((n0 + 1) * KSTEPS + ks) * 64 + lane) * 8);
                acc0 = __builtin_amdgcn_mfma_f32_16x16x32_bf16(a.v, b0, acc0, 0, 0, 0);
                acc1 = __builtin_amdgcn_mfma_f32_16x16x32_bf16(a.v, b1, acc1, 0, 0, 0);
            }
        }

        // ---- dump accs to LDS (C/D: col=lane&15, row=quad*4+reg) ----
        int colb = n0 * 16 + l16;
        int rowb = mb * 16 + quad * 4;
        #pragma unroll
        for (int r = 0; r < 4; r++) {
            gl[rowb + r][colb]      = acc0[r];
            gl[rowb + r][colb + 16] = acc1[r];
        }
        __syncthreads();

        // ---- prefetch next-step xf A-frags (flight hides under epilogue) ----
        {
            int tp = (t < T_STEPS - 1) ? t + 1 : t;      // clamp: no OOB at t=255
            const s16x8* xn = (const s16x8*)xf + ((size_t)tp * 16 + mbg) * KX * 64;
            #pragma unroll
            for (int ks = 0; ks < KX; ks++) xa[ks] = xn[ks * 64 + lane];
        }

        // ---- epilogue: activations + cell + phased gate (fast math) ----
        float hn2[2];
        #pragma unroll
        for (int r = 0; r < 2; r++) {
            int j_l = j0 + r;
            float iv = fsigmoid(gl[b_l][j_l]      + bi[r]);
            float fv = fsigmoid(gl[b_l][16 + j_l] + bff[r]);
            float gv = ftanh_f (gl[b_l][32 + j_l] + bg[r]);
            float ov = fsigmoid(gl[b_l][48 + j_l] + bo[r]);
            float ct = fv * creg[r] + iv * gv;
            float ht = ov * ftanh_f(ct);
            float ph = phs[r];
            float kg = (ph < 0.025f) ? 40.f * ph
                     : ((ph < 0.05f) ? 2.f - 40.f * ph : 0.001f * ph);
            creg[r] = kg * ct + (1.f - kg) * creg[r];
            hreg[r] = kg * ht + (1.f - kg) * hreg[r];
            hn2[r] = hreg[r];
            ph += itau[r];                         // advance phase, wrap
            phs[r] = (ph >= 1.f) ? ph - 1.f : ph;
        }
        unsigned pv = (unsigned)f2bf(hn2[0]) | ((unsigned)f2bf(hn2[1]) << 16);
        if (fast) {
            ((unsigned*)hdst)[pub32] = pv;              // write-through to L2
        } else {
            __hip_atomic_store((unsigned*)hdst + pub32, pv, __ATOMIC_RELAXED,
                               __HIP_MEMORY_SCOPE_AGENT);
        }
        if (t == T_STEPS - 1) {
            hplain[(size_t)bG * HID + jG0]     = hn2[0];
            hplain[(size_t)bG * HID + jG0 + 1] = hn2[1];
        }
        __syncthreads();   // drains vmcnt: publish visible at coherence point

        // ---- group barrier arrive: plain flag store (fast) / atomic (safe) ----
        if (tid == 0) {
            if (fast) {
                *(volatile int*)(flg + hg) = t + 1;     // plain flag store -> L2
            } else {
                __hip_atomic_fetch_add(scnt, 1, __ATOMIC_RELAXED,
                                       __HIP_MEMORY_SCOPE_AGENT);
            }
        }
    }
}

// ---------------------------------------------------------------------------
// FALLBACK persistent kernel (proven) — used when ws_size < WS_NEED.
// ---------------------------------------------------------------------------
__global__ __launch_bounds__(256, 1) void plstm_persist(
    const float* __restrict__ x,
    const unsigned short* __restrict__ Wf,
    unsigned short* __restrict__ hb0,
    unsigned short* __restrict__ hb1,
    float* __restrict__ hplain,
    const float* __restrict__ bias,
    const float* __restrict__ tau,
    const float* __restrict__ shift,
    int* __restrict__ cnt)
{
    __shared__ unsigned short wfl[4 * KSTEPS * 64 * 8];
    __shared__ float gl[32][65];

    int tid = threadIdx.x;
    int lane = tid & 63, w = tid >> 6;
    int mt = blockIdx.x & 7, hg = blockIdx.x >> 3;
    int quad = lane >> 4, l16 = lane & 15;
    int mb = w & 1;
    int n0 = (w >> 1) * 2;

    {
        const s16x8* src = (const s16x8*)(Wf + (size_t)(hg * 4) * KSTEPS * 64 * 8);
        s16x8* dst = (s16x8*)wfl;
        #pragma unroll
        for (int i = 0; i < 36; i++)
            dst[i * 256 + tid] = src[i * 256 + tid];
    }

    int b_l  = tid >> 3;
    int j_l0 = (tid & 7) * 2;
    int bG   = mt * 32 + b_l;
    int jG0  = hg * 16 + j_l0;
    float bi[2], bff[2], bg[2], bo[2], tj[2], sj[2];
    #pragma unroll
    for (int r = 0; r < 2; r++) {
        int jG = jG0 + r;
        bi[r] = bias[jG];        bff[r] = bias[512 + jG];
        bg[r] = bias[1024 + jG]; bo[r] = bias[1536 + jG];
        tj[r] = tau[jG];         sj[r] = shift[jG];
    }
    float creg[2] = {0.f, 0.f}, hreg[2] = {0.f, 0.f};
    size_t pub32;
    {
        int mb2  = bG >> 4, khs2 = jG0 >> 5;
        int ln   = (bG & 15) + ((jG0 >> 3) & 3) * 16;
        pub32 = ((((size_t)mb2 * KH + khs2) * 64 + ln) * 8 + (jG0 & 7)) >> 1;
    }
    __syncthreads();

    int rowA = mt * 32 + mb * 16 + l16;
    int mbg  = mt * 2 + mb;
    int* mycnt = cnt + mt * 32;

    for (int t = 0; t < T_STEPS; t++) {
        f32x4 acc0 = {0.f,0.f,0.f,0.f}, acc1 = acc0;
        #pragma unroll
        for (int ks = 0; ks < KX; ks++) {
            int k = ks * 32 + quad * 8;
            int p = k >> 7, f = k & 127;
            const float* sp = x + ((size_t)(rowA * 5 + p) * 256 + t) * 128 + f;
            float4 u0 = *(const float4*)sp;
            float4 u1 = *(const float4*)(sp + 4);
            s16x8 a = pack8(u0, u1);
            s16x8 b0 = *(const s16x8*)(wfl + (((n0    ) * KSTEPS + ks) * 64 + lane) * 8);
            s16x8 b1 = *(const s16x8*)(wfl + (((n0 + 1) * KSTEPS + ks) * 64 + lane) * 8);
            acc0 = __builtin_amdgcn_mfma_f32_16x16x32_bf16(a, b0, acc0, 0, 0, 0);
            acc1 = __builtin_amdgcn_mfma_f32_16x16x32_bf16(a, b1, acc1, 0, 0, 0);
        }

        if (tid == 0) {
            while (__hip_atomic_load(mycnt, __ATOMIC_RELAXED,
                                     __HIP_MEMORY_SCOPE_AGENT) < 32 * t)
                __builtin_amdgcn_s_sleep(1);
        }
        __syncthreads();

        const unsigned short* hsrc = (t & 1) ? hb1 : hb0;
        unsigned short*       hdst = (t & 1) ? hb0 : hb1;

        const unsigned long long* hq =
            (const unsigned long long*)(hsrc + ((size_t)mbg * KH * 64) * 8);
        #pragma unroll
        for (int khs = 0; khs < KH; khs++) {
            union { unsigned long long q[2]; s16x8 v; } a;
            size_t base = ((size_t)khs * 64 + lane) * 2;
            a.q[0] = __hip_atomic_load(hq + base,     __ATOMIC_RELAXED,
                                       __HIP_MEMORY_SCOPE_AGENT);
            a.q[1] = __hip_atomic_load(hq + base + 1, __ATOMIC_RELAXED,
                                       __HIP_MEMORY_SCOPE_AGENT);
            int ks = KX + khs;
            s16x8 b0 = *(const s16x8*)(wfl + (((n0    ) * KSTEPS + ks) * 64 + lane) * 8);
            s16x8 b1 = *(const s16x8*)(wfl + (((n0 + 1) * KSTEPS + ks) * 64 + lane) * 8);
            acc0 = __builtin_amdgcn_mfma_f32_16x16x32_bf16(a.v, b0, acc0, 0, 0, 0);
            acc1 = __builtin_amdgcn_mfma_f32_16x16x32_bf16(a.v, b1, acc1, 0, 0, 0);
        }

        int colb = n0 * 16 + l16;
        int rowb = mb * 16 + quad * 4;
        #pragma unroll
        for (int r = 0; r < 4; r++) {
            gl[rowb + r][colb]      = acc0[r];
            gl[rowb + r][colb + 16] = acc1[r];
        }
        __syncthreads();

        float hn2[2];
        #pragma unroll
        for (int r = 0; r < 2; r++) {
            int j_l = j_l0 + r;
            float iv = gl[b_l][j_l]      + bi[r];
            float fv = gl[b_l][16 + j_l] + bff[r];
            float gv = gl[b_l][32 + j_l] + bg[r];
            float ov = gl[b_l][48 + j_l] + bo[r];
            iv = 1.f / (1.f + expf(-iv));
            fv = 1.f / (1.f + expf(-fv));
            gv = tanhf(gv);
            ov = 1.f / (1.f + expf(-ov));
            float ct = fv * creg[r] + iv * gv;
            float ht = ov * tanhf(ct);
            float phi = fmodf((float)t - sj[r], tj[r]);
            phi = (phi < 0.f) ? phi + tj[r] : phi;
            phi /= tj[r];
            float kg = (phi < 0.025f) ? 40.f * phi
                     : ((phi < 0.05f) ? 2.f - 40.f * phi : 0.001f * phi);
            creg[r] = kg * ct + (1.f - kg) * creg[r];
            hreg[r] = kg * ht + (1.f - kg) * hreg[r];
            hn2[r] = hreg[r];
        }
        unsigned pv = (unsigned)f2bf(hn2[0]) | ((unsigned)f2bf(hn2[1]) << 16);
        __hip_atomic_store((unsigned*)hdst + pub32, pv, __ATOMIC_RELAXED,
                           __HIP_MEMORY_SCOPE_AGENT);
        if (t == T_STEPS - 1) {
            hplain[(size_t)bG * HID + jG0]     = hn2[0];
            hplain[(size_t)bG * HID + jG0 + 1] = hn2[1];
        }
        __syncthreads();

        if (tid == 0)
            __hip_atomic_fetch_add(mycnt, 1, __ATOMIC_RELAXED,
                                   __HIP_MEMORY_SCOPE_AGENT);
    }
}

// ---------------------------------------------------------------------------
// Final FC (512 -> 60) + log_softmax. One wave per batch row.
// ---------------------------------------------------------------------------
__global__ __launch_bounds__(64) void fc_kernel(
    const float* __restrict__ hplain, const float* __restrict__ fcw,
    const float* __restrict__ fcb, float* __restrict__ out)
{
    int b = blockIdx.x, lane = threadIdx.x;
    float logit = -INFINITY;
    if (lane < NCLASS) {
        float s = fcb[lane];
        const float* hp = hplain + (size_t)b * HID;
        #pragma unroll 8
        for (int k = 0; k < HID; k++)
            s += hp[k] * fcw[(size_t)k * NCLASS + lane];
        logit = s;
    }
    float m = logit;
    for (int off = 32; off > 0; off >>= 1)
        m = fmaxf(m, __shfl_xor(m, off, 64));
    float e = (lane < NCLASS) ? expf(logit - m) : 0.f;
    float se = e;
    for (int off = 32; off > 0; off >>= 1)
        se += __shfl_xor(se, off, 64);
    if (lane < NCLASS)
        out[(size_t)b * NCLASS + lane] = logit - m - logf(se);
}

extern "C" void kernel_launch(void* const* d_in, const int* in_sizes, int n_in,
                              void* d_out, int out_size, void* d_ws, size_t ws_size,
                              hipStream_t stream)
{
    const float* x     = (const float*)d_in[0];
    const float* Wx    = (const float*)d_in[1];
    const float* Wh    = (const float*)d_in[2];
    const float* bias  = (const float*)d_in[3];
    const float* tau   = (const float*)d_in[4];
    const float* shift = (const float*)d_in[5];
    const float* fcw   = (const float*)d_in[6];
    const float* fcb   = (const float*)d_in[7];
    float* out = (float*)d_out;
    char* ws = (char*)d_ws;

    int*            ctl    = (int*)ws;
    unsigned short* Wf     = (unsigned short*)(ws + WF_OFF);
    unsigned short* hb0    = (unsigned short*)(ws + HB0_OFF);
    unsigned short* hb1    = (unsigned short*)(ws + HB1_OFF);
    float*          hplain = (float*)(ws + HPL_OFF);
    unsigned short* xfb    = (unsigned short*)(ws + XF_OFF);

    hipMemsetAsync(ws, 0, 4096, stream);                 // control block
    hipMemsetAsync(ws + HB0_OFF, 0, 262144, stream);     // h0 = 0

    pack_w_kernel<<<dim3(1152), dim3(256), 0, stream>>>(Wx, Wh, Wf);

    if (ws_size >= WS_NEED) {
        xf_kernel<<<dim3(4096), dim3(256), 0, stream>>>(x, xfb);
        plstm_persist3<<<dim3(256), dim3(256), 0, stream>>>(
            xfb, Wf, hb0, hb1, hplain, bias, tau, shift, ctl);
    } else {
        plstm_persist<<<dim3(256), dim3(256), 0, stream>>>(
            x, Wf, hb0, hb1, hplain, bias, tau, shift, ctl);
    }

    fc_kernel<<<dim3(256), dim3(64), 0, stream>>>(hplain, fcw, fcb, out);
}

// Round 7
// 1096.297 us; speedup vs baseline: 1.1444x; 1.0080x over previous
//
#include <hip/hip_runtime.h>
#include <math.h>

// Problem constants
#define T_STEPS 256
#define BATCH   256
#define HID     512
#define DIN     640     // P*F = 5*128
#define NCOL    2048    // 4*H
#define NCLASS  60
#define KSTEPS  36      // 1152 / 32
#define KX      20      // x-part k-steps (640/32)
#define KH      16      // h-part k-steps (512/32)

typedef float f32x4 __attribute__((ext_vector_type(4)));
typedef short s16x8 __attribute__((ext_vector_type(8)));

// ws layout (bytes):
//   [0,        4096)      control: safecnt[8*32] ints @0, fastcnt[8*32] ints @1024,
//                         precnt @2048, xccbuf[256] ints @2176
//   [4096,     4722688)   Wf  bf16 packed weights (128*36*64*8 shorts)
//   [4722688,  4984832)   hb0 bf16 h frag buffer (256 KB)
//   [4984832,  5246976)   hb1 bf16 h frag buffer
//   [5246976,  5771264)   hplain fp32 (256x512)
//   [5771264,  89657344)  xf  bf16 x A-frags [t][mbg][ks][lane][8] (84 MB)
#define WF_OFF   4096
#define HB0_OFF  4722688
#define HB1_OFF  4984832
#define HPL_OFF  5246976
#define XF_OFF   5771264
#define WS_NEED  89657344ULL

__device__ __forceinline__ unsigned short f2bf(float x) {
    union { float f; unsigned u; } v; v.f = x;
    unsigned r = v.u + 0x7fffu + ((v.u >> 16) & 1u);   // round-to-nearest-even
    return (unsigned short)(r >> 16);
}

__device__ __forceinline__ s16x8 pack8(float4 a, float4 b) {
    s16x8 r;
    r[0] = (short)f2bf(a.x); r[1] = (short)f2bf(a.y);
    r[2] = (short)f2bf(a.z); r[3] = (short)f2bf(a.w);
    r[4] = (short)f2bf(b.x); r[5] = (short)f2bf(b.y);
    r[6] = (short)f2bf(b.z); r[7] = (short)f2bf(b.w);
    return r;
}

// Fast-math activations. Mathematically exact formulas; only v_exp/v_rcp
// rounding (~1e-7 rel) differs from libm — far below the bf16 h-exchange
// quantization already present.
__device__ __forceinline__ float fsigmoid(float x) {
    return __builtin_amdgcn_rcpf(1.f + __expf(-x));
}
__device__ __forceinline__ float ftanh_f(float x) {
    float e = __expf(-2.f * fabsf(x));
    float r = (1.f - e) * __builtin_amdgcn_rcpf(1.f + e);
    return copysignf(r, x);
}

// ---------------------------------------------------------------------------
// Pack [Wx; Wh] (1152 x 2048 fp32) into bf16 B-fragment-linear layout.
// ---------------------------------------------------------------------------
__global__ __launch_bounds__(256) void pack_w_kernel(
    const float* __restrict__ Wx, const float* __restrict__ Wh,
    unsigned short* __restrict__ Wf)
{
    int g = blockIdx.x * 256 + threadIdx.x;      // [0, 128*36*64)
    int nb  = g / (KSTEPS * 64);
    int rem = g - nb * (KSTEPS * 64);
    int ks = rem >> 6;
    int lane = rem & 63;
    int gate = nb & 3, hg = nb >> 2;
    int n = gate * 512 + hg * 16 + (lane & 15);
    int kbase = ks * 32 + (lane >> 4) * 8;
    s16x8 frag;
    #pragma unroll
    for (int j = 0; j < 8; j++) {
        int k = kbase + j;
        float v = (k < DIN) ? Wx[(size_t)k * NCOL + n]
                            : Wh[(size_t)(k - DIN) * NCOL + n];
        frag[j] = (short)f2bf(v);
    }
    *(s16x8*)(Wf + (size_t)g * 8) = frag;
}

// ---------------------------------------------------------------------------
// Pre-convert x to bf16 A-fragment layout: xf[((t*16+mbg)*20+ks)*64+lane][8]
// ---------------------------------------------------------------------------
__global__ __launch_bounds__(256) void xf_kernel(
    const float* __restrict__ x, unsigned short* __restrict__ xf)
{
    int bid = blockIdx.x;            // t*16 + mbg
    int t = bid >> 4, mbg = bid & 15;
    for (int it = threadIdx.x; it < 1280; it += 256) {
        int ks = it >> 6, lane = it & 63;
        int row = mbg * 16 + (lane & 15);
        int k = ks * 32 + (lane >> 4) * 8;
        int p = k >> 7, f = k & 127;
        const float* sp = x + ((size_t)(row * 5 + p) * 256 + t) * 128 + f;
        float4 u0 = *(const float4*)sp;
        float4 u1 = *(const float4*)(sp + 4);
        s16x8 o = pack8(u0, u1);
        *(s16x8*)(xf + ((size_t)bid * 1280 + it) * 8) = o;
    }
}

// ---------------------------------------------------------------------------
// Persistent phased-LSTM. 256 WGs x 256 thr, 1 WG/CU. WG=(mt=bid&7, hg=bid>>3).
// Byte-identical to the proven 780µs R2 kernel EXCEPT one dataflow change in
// the fast h-phase: the next-step xf register prefetch is issued right after
// the 16 h loads (plain C loads, compiler-managed waitcnts) instead of after
// the dump-sync. Cover before the publish __syncthreads' vmcnt(0) drain grows
// from ~350cy (epilogue only) to ~1000cy (h-MFMA + dump + epilogue), so the
// drain waits ~zero residual xf latency. No inline-asm loads, no manual
// vmcnt, no barrier/protocol changes (R6's crash lesson).
// FAST protocol (proven): plain write-through h publish -> XCD L2;
//   buffer_inv + plain loads; single global_atomic_add counter arrive;
//   tid0 buffer_inv+load poll.
// SAFE (fallback, proven): relaxed agent-scope atomics at LLC.
// ---------------------------------------------------------------------------
__global__ __launch_bounds__(256, 1) void plstm_persist3(
    const unsigned short* __restrict__ xf,
    const unsigned short* __restrict__ Wf,
    unsigned short* __restrict__ hb0,
    unsigned short* __restrict__ hb1,
    float* __restrict__ hplain,
    const float* __restrict__ bias,
    const float* __restrict__ tau,
    const float* __restrict__ shift,
    int* __restrict__ ctl)
{
    __shared__ unsigned short wfl[4 * KSTEPS * 64 * 8];  // 147456 B
    __shared__ float gl[32][65];                          // 8320 B
    __shared__ int protflag;

    int tid = threadIdx.x;
    int lane = tid & 63, w = tid >> 6;
    int bid = blockIdx.x;
    int mt = bid & 7, hg = bid >> 3;
    int quad = lane >> 4, l16 = lane & 15;
    int mb = w & 1;
    int n0 = (w >> 1) * 2;

    // --- XCD-uniformity handshake (one-time) ---
    int xcc = __builtin_amdgcn_s_getreg((31 << 11) | (0 << 6) | 20); // HW_REG_XCC_ID
    if (tid == 0) {
        __hip_atomic_store(&ctl[544 + bid], xcc + 1, __ATOMIC_RELAXED,
                           __HIP_MEMORY_SCOPE_AGENT);
        asm volatile("s_waitcnt vmcnt(0)" ::: "memory");
        __hip_atomic_fetch_add(&ctl[512], 1, __ATOMIC_RELAXED,
                               __HIP_MEMORY_SCOPE_AGENT);
        while (__hip_atomic_load(&ctl[512], __ATOMIC_RELAXED,
                                 __HIP_MEMORY_SCOPE_AGENT) < 256)
            __builtin_amdgcn_s_sleep(1);
    }

    // --- stage weight slice into LDS (overlaps handshake) ---
    {
        const s16x8* src = (const s16x8*)(Wf + (size_t)(hg * 4) * KSTEPS * 64 * 8);
        s16x8* dst = (s16x8*)wfl;
        #pragma unroll
        for (int i = 0; i < 36; i++)
            dst[i * 256 + tid] = src[i * 256 + tid];
    }
    __syncthreads();

    if (w == 0) {
        int pred = 1;
        if (lane < 32) {
            int v = __hip_atomic_load(&ctl[544 + mt + 8 * lane], __ATOMIC_RELAXED,
                                      __HIP_MEMORY_SCOPE_AGENT);
            pred = (v == xcc + 1);
        }
        unsigned long long bal = __ballot(pred);
        if (lane == 0) protflag = (bal == ~0ull) ? 1 : 0;
    }
    __syncthreads();
    int fast = protflag;

    // --- per-thread epilogue constants + register state (2 cells) ---
    int b_l = tid >> 3;
    int j0  = (tid & 7) * 2;
    int bG  = mt * 32 + b_l;
    int jG0 = hg * 16 + j0;
    float bi[2], bff[2], bg[2], bo[2], phs[2], itau[2];
    #pragma unroll
    for (int r = 0; r < 2; r++) {
        int jG = jG0 + r;
        bi[r] = bias[jG];        bff[r] = bias[512 + jG];
        bg[r] = bias[1024 + jG]; bo[r] = bias[1536 + jG];
        float tj = tau[jG], sj = shift[jG];
        itau[r] = 1.f / tj;                      // precise divide, once
        float ph = fmodf(-sj, tj);
        ph = (ph < 0.f) ? ph + tj : ph;
        phs[r] = ph * itau[r];                   // phi at t=0; advanced by itau/step
    }
    float creg[2] = {0.f, 0.f}, hreg[2] = {0.f, 0.f};
    size_t pub32;
    {
        int mb2 = bG >> 4, khs2 = jG0 >> 5;
        int ln  = (bG & 15) + ((jG0 >> 3) & 3) * 16;
        pub32 = ((((size_t)mb2 * KH + khs2) * 64 + ln) * 8 + (jG0 & 7)) >> 1;
    }

    int mbg = mt * 2 + mb;
    volatile int* fcv = (volatile int*)&ctl[256 + mt * 32];
    unsigned long long fca = (unsigned long long)(ctl + 256 + mt * 32);
    int* scnt = &ctl[mt * 32];

    // --- preload xf A-frags for t=0 into registers ---
    s16x8 xa[KX];
    {
        const s16x8* x0 = (const s16x8*)xf + (size_t)mbg * KX * 64;
        #pragma unroll
        for (int ks = 0; ks < KX; ks++) xa[ks] = x0[ks * 64 + lane];
    }

    for (int t = 0; t < T_STEPS; t++) {
        // ---- x phase: MFMA from register-prefetched A-frags ----
        f32x4 acc0 = {0.f, 0.f, 0.f, 0.f}, acc1 = acc0;
        #pragma unroll
        for (int ks = 0; ks < KX; ks++) {
            s16x8 b0 = *(const s16x8*)(wfl + (((n0    ) * KSTEPS + ks) * 64 + lane) * 8);
            s16x8 b1 = *(const s16x8*)(wfl + (((n0 + 1) * KSTEPS + ks) * 64 + lane) * 8);
            acc0 = __builtin_amdgcn_mfma_f32_16x16x32_bf16(xa[ks], b0, acc0, 0, 0, 0);
            acc1 = __builtin_amdgcn_mfma_f32_16x16x32_bf16(xa[ks], b1, acc1, 0, 0, 0);
        }

        // ---- group barrier wait (R2-proven protocol) ----
        if (tid == 0) {
            if (fast) {
                int v;
                do {
                    asm volatile("buffer_inv" ::: "memory");  // drop CU L1
                    v = *fcv;                                  // plain load -> L2
                } while (v < 32 * t);
            } else {
                while (__hip_atomic_load(scnt, __ATOMIC_RELAXED,
                                         __HIP_MEMORY_SCOPE_AGENT) < 32 * t)
                    __builtin_amdgcn_s_sleep(1);
            }
        }
        __syncthreads();

        const unsigned short* hsrc = (t & 1) ? hb1 : hb0;
        unsigned short*       hdst = (t & 1) ? hb0 : hb1;

        // ---- h phase ----
        if (fast) {
            asm volatile("buffer_inv" ::: "memory");   // per-wave L1 invalidate
            const s16x8* hs = (const s16x8*)hsrc + (size_t)mbg * KH * 64;
            // (1) h loads (batched; compiler pipelines + inserts counted waits)
            s16x8 ha[KH];
            #pragma unroll
            for (int khs = 0; khs < KH; khs++)
                ha[khs] = hs[khs * 64 + lane];
            // (2) next-step xf prefetch issued HERE: the h-MFMAs + dump +
            //     epilogue (~1000cy) cover its L3 latency before the publish
            //     __syncthreads drains vmcnt(0). (R2 paid ~350cy residual by
            //     issuing post-dump; R4 showed pre-poll issue is fatal.)
            {
                int tp = (t < T_STEPS - 1) ? t + 1 : t;  // clamp: no OOB at t=255
                const s16x8* xn = (const s16x8*)xf + ((size_t)tp * 16 + mbg) * KX * 64;
                #pragma unroll
                for (int ks = 0; ks < KX; ks++) xa[ks] = xn[ks * 64 + lane];
            }
            // (3) h-MFMAs
            #pragma unroll
            for (int khs = 0; khs < KH; khs++) {
                int ks = KX + khs;
                s16x8 b0 = *(const s16x8*)(wfl + (((n0    ) * KSTEPS + ks) * 64 + lane) * 8);
                s16x8 b1 = *(const s16x8*)(wfl + (((n0 + 1) * KSTEPS + ks) * 64 + lane) * 8);
                acc0 = __builtin_amdgcn_mfma_f32_16x16x32_bf16(ha[khs], b0, acc0, 0, 0, 0);
                acc1 = __builtin_amdgcn_mfma_f32_16x16x32_bf16(ha[khs], b1, acc1, 0, 0, 0);
            }
        } else {
            const unsigned long long* hq =
                (const unsigned long long*)(hsrc + ((size_t)mbg * KH * 64) * 8);
            #pragma unroll
            for (int khs = 0; khs < KH; khs++) {
                union { unsigned long long q[2]; s16x8 v; } a;
                size_t base = ((size_t)khs * 64 + lane) * 2;
                a.q[0] = __hip_atomic_load(hq + base,     __ATOMIC_RELAXED,
                                           __HIP_MEMORY_SCOPE_AGENT);
                a.q[1] = __hip_atomic_load(hq + base + 1, __ATOMIC_RELAXED,
                                           __HIP_MEMORY_SCOPE_AGENT);
                int ks = KX + khs;
                s16x8 b0 = *(const s16x8*)(wfl + (((n0    ) * KSTEPS + ks) * 64 + lane) * 8);
                s16x8 b1 = *(const s16x8*)(wfl + (((n0 + 1) * KSTEPS + ks) * 64 + lane) * 8);
                acc0 = __builtin_amdgcn_mfma_f32_16x16x32_bf16(a.v, b0, acc0, 0, 0, 0);
                acc1 = __builtin_amdgcn_mfma_f32_16x16x32_bf16(a.v, b1, acc1, 0, 0, 0);
            }
        }

        // ---- dump accs to LDS (C/D: col=lane&15, row=quad*4+reg) ----
        int colb = n0 * 16 + l16;
        int rowb = mb * 16 + quad * 4;
        #pragma unroll
        for (int r = 0; r < 4; r++) {
            gl[rowb + r][colb]      = acc0[r];
            gl[rowb + r][colb + 16] = acc1[r];
        }
        __syncthreads();

        // ---- safe path: xf prefetch at the R2 position ----
        if (!fast) {
            int tp = (t < T_STEPS - 1) ? t + 1 : t;
            const s16x8* xn = (const s16x8*)xf + ((size_t)tp * 16 + mbg) * KX * 64;
            #pragma unroll
            for (int ks = 0; ks < KX; ks++) xa[ks] = xn[ks * 64 + lane];
        }

        // ---- epilogue: activations + cell + phased gate (fast math) ----
        float hn2[2];
        #pragma unroll
        for (int r = 0; r < 2; r++) {
            int j_l = j0 + r;
            float iv = fsigmoid(gl[b_l][j_l]      + bi[r]);
            float fv = fsigmoid(gl[b_l][16 + j_l] + bff[r]);
            float gv = ftanh_f (gl[b_l][32 + j_l] + bg[r]);
            float ov = fsigmoid(gl[b_l][48 + j_l] + bo[r]);
            float ct = fv * creg[r] + iv * gv;
            float ht = ov * ftanh_f(ct);
            float ph = phs[r];
            float kg = (ph < 0.025f) ? 40.f * ph
                     : ((ph < 0.05f) ? 2.f - 40.f * ph : 0.001f * ph);
            creg[r] = kg * ct + (1.f - kg) * creg[r];
            hreg[r] = kg * ht + (1.f - kg) * hreg[r];
            hn2[r] = hreg[r];
            ph += itau[r];                         // advance phase, wrap
            phs[r] = (ph >= 1.f) ? ph - 1.f : ph;
        }
        unsigned pv = (unsigned)f2bf(hn2[0]) | ((unsigned)f2bf(hn2[1]) << 16);
        if (fast) {
            ((unsigned*)hdst)[pub32] = pv;              // write-through to L2
        } else {
            __hip_atomic_store((unsigned*)hdst + pub32, pv, __ATOMIC_RELAXED,
                               __HIP_MEMORY_SCOPE_AGENT);
        }
        if (t == T_STEPS - 1) {
            hplain[(size_t)bG * HID + jG0]     = hn2[0];
            hplain[(size_t)bG * HID + jG0 + 1] = hn2[1];
        }
        __syncthreads();   // drains vmcnt: publish visible at coherence point;
                           // xf loads issued a full h-phase earlier ≈ retired

        // ---- group barrier arrive (R2-proven protocol) ----
        if (tid == 0) {
            if (fast) {
                int one = 1;
                asm volatile("global_atomic_add %0, %1, off"
                             :: "v"(fca), "v"(one) : "memory");  // L2-executed
            } else {
                __hip_atomic_fetch_add(scnt, 1, __ATOMIC_RELAXED,
                                       __HIP_MEMORY_SCOPE_AGENT);
            }
        }
    }
}

// ---------------------------------------------------------------------------
// FALLBACK persistent kernel (proven) — used when ws_size < WS_NEED.
// ---------------------------------------------------------------------------
__global__ __launch_bounds__(256, 1) void plstm_persist(
    const float* __restrict__ x,
    const unsigned short* __restrict__ Wf,
    unsigned short* __restrict__ hb0,
    unsigned short* __restrict__ hb1,
    float* __restrict__ hplain,
    const float* __restrict__ bias,
    const float* __restrict__ tau,
    const float* __restrict__ shift,
    int* __restrict__ cnt)
{
    __shared__ unsigned short wfl[4 * KSTEPS * 64 * 8];
    __shared__ float gl[32][65];

    int tid = threadIdx.x;
    int lane = tid & 63, w = tid >> 6;
    int mt = blockIdx.x & 7, hg = blockIdx.x >> 3;
    int quad = lane >> 4, l16 = lane & 15;
    int mb = w & 1;
    int n0 = (w >> 1) * 2;

    {
        const s16x8* src = (const s16x8*)(Wf + (size_t)(hg * 4) * KSTEPS * 64 * 8);
        s16x8* dst = (s16x8*)wfl;
        #pragma unroll
        for (int i = 0; i < 36; i++)
            dst[i * 256 + tid] = src[i * 256 + tid];
    }

    int b_l  = tid >> 3;
    int j_l0 = (tid & 7) * 2;
    int bG   = mt * 32 + b_l;
    int jG0  = hg * 16 + j_l0;
    float bi[2], bff[2], bg[2], bo[2], tj[2], sj[2];
    #pragma unroll
    for (int r = 0; r < 2; r++) {
        int jG = jG0 + r;
        bi[r] = bias[jG];        bff[r] = bias[512 + jG];
        bg[r] = bias[1024 + jG]; bo[r] = bias[1536 + jG];
        tj[r] = tau[jG];         sj[r] = shift[jG];
    }
    float creg[2] = {0.f, 0.f}, hreg[2] = {0.f, 0.f};
    size_t pub32;
    {
        int mb2  = bG >> 4, khs2 = jG0 >> 5;
        int ln   = (bG & 15) + ((jG0 >> 3) & 3) * 16;
        pub32 = ((((size_t)mb2 * KH + khs2) * 64 + ln) * 8 + (jG0 & 7)) >> 1;
    }
    __syncthreads();

    int rowA = mt * 32 + mb * 16 + l16;
    int mbg  = mt * 2 + mb;
    int* mycnt = cnt + mt * 32;

    for (int t = 0; t < T_STEPS; t++) {
        f32x4 acc0 = {0.f,0.f,0.f,0.f}, acc1 = acc0;
        #pragma unroll
        for (int ks = 0; ks < KX; ks++) {
            int k = ks * 32 + quad * 8;
            int p = k >> 7, f = k & 127;
            const float* sp = x + ((size_t)(rowA * 5 + p) * 256 + t) * 128 + f;
            float4 u0 = *(const float4*)sp;
            float4 u1 = *(const float4*)(sp + 4);
            s16x8 a = pack8(u0, u1);
            s16x8 b0 = *(const s16x8*)(wfl + (((n0    ) * KSTEPS + ks) * 64 + lane) * 8);
            s16x8 b1 = *(const s16x8*)(wfl + (((n0 + 1) * KSTEPS + ks) * 64 + lane) * 8);
            acc0 = __builtin_amdgcn_mfma_f32_16x16x32_bf16(a, b0, acc0, 0, 0, 0);
            acc1 = __builtin_amdgcn_mfma_f32_16x16x32_bf16(a, b1, acc1, 0, 0, 0);
        }

        if (tid == 0) {
            while (__hip_atomic_load(mycnt, __ATOMIC_RELAXED,
                                     __HIP_MEMORY_SCOPE_AGENT) < 32 * t)
                __builtin_amdgcn_s_sleep(1);
        }
        __syncthreads();

        const unsigned short* hsrc = (t & 1) ? hb1 : hb0;
        unsigned short*       hdst = (t & 1) ? hb0 : hb1;

        const unsigned long long* hq =
            (const unsigned long long*)(hsrc + ((size_t)mbg * KH * 64) * 8);
        #pragma unroll
        for (int khs = 0; khs < KH; khs++) {
            union { unsigned long long q[2]; s16x8 v; } a;
            size_t base = ((size_t)khs * 64 + lane) * 2;
            a.q[0] = __hip_atomic_load(hq + base,     __ATOMIC_RELAXED,
                                       __HIP_MEMORY_SCOPE_AGENT);
            a.q[1] = __hip_atomic_load(hq + base + 1, __ATOMIC_RELAXED,
                                       __HIP_MEMORY_SCOPE_AGENT);
            int ks = KX + khs;
            s16x8 b0 = *(const s16x8*)(wfl + (((n0    ) * KSTEPS + ks) * 64 + lane) * 8);
            s16x8 b1 = *(const s16x8*)(wfl + (((n0 + 1) * KSTEPS + ks) * 64 + lane) * 8);
            acc0 = __builtin_amdgcn_mfma_f32_16x16x32_bf16(a.v, b0, acc0, 0, 0, 0);
            acc1 = __builtin_amdgcn_mfma_f32_16x16x32_bf16(a.v, b1, acc1, 0, 0, 0);
        }

        int colb = n0 * 16 + l16;
        int rowb = mb * 16 + quad * 4;
        #pragma unroll
        for (int r = 0; r < 4; r++) {
            gl[rowb + r][colb]      = acc0[r];
            gl[rowb + r][colb + 16] = acc1[r];
        }
        __syncthreads();

        float hn2[2];
        #pragma unroll
        for (int r = 0; r < 2; r++) {
            int j_l = j_l0 + r;
            float iv = gl[b_l][j_l]      + bi[r];
            float fv = gl[b_l][16 + j_l] + bff[r];
            float gv = gl[b_l][32 + j_l] + bg[r];
            float ov = gl[b_l][48 + j_l] + bo[r];
            iv = 1.f / (1.f + expf(-iv));
            fv = 1.f / (1.f + expf(-fv));
            gv = tanhf(gv);
            ov = 1.f / (1.f + expf(-ov));
            float ct = fv * creg[r] + iv * gv;
            float ht = ov * tanhf(ct);
            float phi = fmodf((float)t - sj[r], tj[r]);
            phi = (phi < 0.f) ? phi + tj[r] : phi;
            phi /= tj[r];
            float kg = (phi < 0.025f) ? 40.f * phi
                     : ((phi < 0.05f) ? 2.f - 40.f * phi : 0.001f * phi);
            creg[r] = kg * ct + (1.f - kg) * creg[r];
            hreg[r] = kg * ht + (1.f - kg) * hreg[r];
            hn2[r] = hreg[r];
        }
        unsigned pv = (unsigned)f2bf(hn2[0]) | ((unsigned)f2bf(hn2[1]) << 16);
        __hip_atomic_store((unsigned*)hdst + pub32, pv, __ATOMIC_RELAXED,
                           __HIP_MEMORY_SCOPE_AGENT);
        if (t == T_STEPS - 1) {
            hplain[(size_t)bG * HID + jG0]     = hn2[0];
            hplain[(size_t)bG * HID + jG0 + 1] = hn2[1];
        }
        __syncthreads();

        if (tid == 0)
            __hip_atomic_fetch_add(mycnt, 1, __ATOMIC_RELAXED,
                                   __HIP_MEMORY_SCOPE_AGENT);
    }
}

// ---------------------------------------------------------------------------
// Final FC (512 -> 60) + log_softmax. One wave per batch row.
// ---------------------------------------------------------------------------
__global__ __launch_bounds__(64) void fc_kernel(
    const float* __restrict__ hplain, const float* __restrict__ fcw,
    const float* __restrict__ fcb, float* __restrict__ out)
{
    int b = blockIdx.x, lane = threadIdx.x;
    float logit = -INFINITY;
    if (lane < NCLASS) {
        float s = fcb[lane];
        const float* hp = hplain + (size_t)b * HID;
        #pragma unroll 8
        for (int k = 0; k < HID; k++)
            s += hp[k] * fcw[(size_t)k * NCLASS + lane];
        logit = s;
    }
    float m = logit;
    for (int off = 32; off > 0; off >>= 1)
        m = fmaxf(m, __shfl_xor(m, off, 64));
    float e = (lane < NCLASS) ? expf(logit - m) : 0.f;
    float se = e;
    for (int off = 32; off > 0; off >>= 1)
        se += __shfl_xor(se, off, 64);
    if (lane < NCLASS)
        out[(size_t)b * NCLASS + lane] = logit - m - logf(se);
}

extern "C" void kernel_launch(void* const* d_in, const int* in_sizes, int n_in,
                              void* d_out, int out_size, void* d_ws, size_t ws_size,
                              hipStream_t stream)
{
    const float* x     = (const float*)d_in[0];
    const float* Wx    = (const float*)d_in[1];
    const float* Wh    = (const float*)d_in[2];
    const float* bias  = (const float*)d_in[3];
    const float* tau   = (const float*)d_in[4];
    const float* shift = (const float*)d_in[5];
    const float* fcw   = (const float*)d_in[6];
    const float* fcb   = (const float*)d_in[7];
    float* out = (float*)d_out;
    char* ws = (char*)d_ws;

    int*            ctl    = (int*)ws;
    unsigned short* Wf     = (unsigned short*)(ws + WF_OFF);
    unsigned short* hb0    = (unsigned short*)(ws + HB0_OFF);
    unsigned short* hb1    = (unsigned short*)(ws + HB1_OFF);
    float*          hplain = (float*)(ws + HPL_OFF);
    unsigned short* xfb    = (unsigned short*)(ws + XF_OFF);

    hipMemsetAsync(ws, 0, 4096, stream);                 // control block
    hipMemsetAsync(ws + HB0_OFF, 0, 262144, stream);     // h0 = 0

    pack_w_kernel<<<dim3(1152), dim3(256), 0, stream>>>(Wx, Wh, Wf);

    if (ws_size >= WS_NEED) {
        xf_kernel<<<dim3(4096), dim3(256), 0, stream>>>(x, xfb);
        plstm_persist3<<<dim3(256), dim3(256), 0, stream>>>(
            xfb, Wf, hb0, hb1, hplain, bias, tau, shift, ctl);
    } else {
        plstm_persist<<<dim3(256), dim3(256), 0, stream>>>(
            x, Wf, hb0, hb1, hplain, bias, tau, shift, ctl);
    }

    fc_kernel<<<dim3(256), dim3(64), 0, stream>>>(hplain, fcw, fcb, out);
}

// Round 8
// 1022.630 us; speedup vs baseline: 1.2269x; 1.0720x over previous
//
#include <hip/hip_runtime.h>
#include <math.h>

// Problem constants
#define T_STEPS 256
#define BATCH   256
#define HID     512
#define DIN     640     // P*F = 5*128
#define NCOL    2048    // 4*H
#define NCLASS  60
#define KSTEPS  36      // 1152 / 32
#define KX      20      // x-part k-steps (640/32)
#define KH      16      // h-part k-steps (512/32)

typedef float f32x4 __attribute__((ext_vector_type(4)));
typedef short s16x8 __attribute__((ext_vector_type(8)));

// ws layout (bytes):
//   [0,        4096)      control: safecnt[8*32] ints @0, fastcnt[8*32] ints @1024,
//                         precnt @2048, xccbuf[256] ints @2176
//   [4096,     4722688)   Wf  bf16 packed weights (128*36*64*8 shorts)
//   [4722688,  4984832)   hb0 bf16 h frag buffer (256 KB)
//   [4984832,  5246976)   hb1 bf16 h frag buffer
//   [5246976,  5771264)   hplain fp32 (256x512)
//   [5771264,  89657344)  xf  bf16 x A-frags [t][mbg][ks][lane][8] (84 MB)
#define WF_OFF   4096
#define HB0_OFF  4722688
#define HB1_OFF  4984832
#define HPL_OFF  5246976
#define XF_OFF   5771264
#define WS_NEED  89657344ULL

__device__ __forceinline__ unsigned short f2bf(float x) {
    union { float f; unsigned u; } v; v.f = x;
    unsigned r = v.u + 0x7fffu + ((v.u >> 16) & 1u);   // round-to-nearest-even
    return (unsigned short)(r >> 16);
}

__device__ __forceinline__ s16x8 pack8(float4 a, float4 b) {
    s16x8 r;
    r[0] = (short)f2bf(a.x); r[1] = (short)f2bf(a.y);
    r[2] = (short)f2bf(a.z); r[3] = (short)f2bf(a.w);
    r[4] = (short)f2bf(b.x); r[5] = (short)f2bf(b.y);
    r[6] = (short)f2bf(b.z); r[7] = (short)f2bf(b.w);
    return r;
}

// Fast-math activations. Mathematically exact formulas; only v_exp/v_rcp
// rounding (~1e-7 rel) differs from libm — far below the bf16 h-exchange
// quantization already present. Both overflow-safe (exp of non-positive arg
// for tanh; rcp(inf)=0 for sigmoid).
__device__ __forceinline__ float fsigmoid(float x) {
    return __builtin_amdgcn_rcpf(1.f + __expf(-x));
}
__device__ __forceinline__ float ftanh_f(float x) {
    float e = __expf(-2.f * fabsf(x));
    float r = (1.f - e) * __builtin_amdgcn_rcpf(1.f + e);
    return copysignf(r, x);
}

// ---------------------------------------------------------------------------
// Pack [Wx; Wh] (1152 x 2048 fp32) into bf16 B-fragment-linear layout.
// ---------------------------------------------------------------------------
__global__ __launch_bounds__(256) void pack_w_kernel(
    const float* __restrict__ Wx, const float* __restrict__ Wh,
    unsigned short* __restrict__ Wf)
{
    int g = blockIdx.x * 256 + threadIdx.x;      // [0, 128*36*64)
    int nb  = g / (KSTEPS * 64);
    int rem = g - nb * (KSTEPS * 64);
    int ks = rem >> 6;
    int lane = rem & 63;
    int gate = nb & 3, hg = nb >> 2;
    int n = gate * 512 + hg * 16 + (lane & 15);
    int kbase = ks * 32 + (lane >> 4) * 8;
    s16x8 frag;
    #pragma unroll
    for (int j = 0; j < 8; j++) {
        int k = kbase + j;
        float v = (k < DIN) ? Wx[(size_t)k * NCOL + n]
                            : Wh[(size_t)(k - DIN) * NCOL + n];
        frag[j] = (short)f2bf(v);
    }
    *(s16x8*)(Wf + (size_t)g * 8) = frag;
}

// ---------------------------------------------------------------------------
// Pre-convert x to bf16 A-fragment layout: xf[((t*16+mbg)*20+ks)*64+lane][8]
// row = mbg*16 + (lane&15), k = ks*32 + (lane>>4)*8 + j. One pass over x.
// ---------------------------------------------------------------------------
__global__ __launch_bounds__(256) void xf_kernel(
    const float* __restrict__ x, unsigned short* __restrict__ xf)
{
    int bid = blockIdx.x;            // t*16 + mbg
    int t = bid >> 4, mbg = bid & 15;
    for (int it = threadIdx.x; it < 1280; it += 256) {
        int ks = it >> 6, lane = it & 63;
        int row = mbg * 16 + (lane & 15);
        int k = ks * 32 + (lane >> 4) * 8;
        int p = k >> 7, f = k & 127;
        const float* sp = x + ((size_t)(row * 5 + p) * 256 + t) * 128 + f;
        float4 u0 = *(const float4*)sp;
        float4 u1 = *(const float4*)(sp + 4);
        s16x8 o = pack8(u0, u1);
        *(s16x8*)(xf + ((size_t)bid * 1280 + it) * 8) = o;
    }
}

// ---------------------------------------------------------------------------
// Persistent phased-LSTM. 256 WGs x 256 thr, 1 WG/CU. WG=(mt=bid&7, hg=bid>>3).
// Full Wf slice (36 ksteps) in LDS. Per-group protocol chosen at runtime:
//   FAST (all 32 members share an XCD, verified via HW_REG_XCC_ID): h exchange
//     through the XCD's L2 — plain write-through stores, buffer_inv (L1-only)
//     + plain coalesced loads, plain global_atomic_add (L2-executed) barrier.
//   SAFE (fallback, proven): relaxed agent-scope atomics at LLC.
// Proven-best configuration (R2, 780µs): xf A-frags register-prefetched one
// step ahead at the post-dump position (epilogue covers most of the L3
// latency; every placement variant tried — pre-poll, top-of-step, in-h-phase
// — regressed by 90-240µs). Fast-math epilogue (v_exp/v_rcp, incremental
// phase recurrence). Single-dword atomic-counter barrier (flag-array variant
// measured +85µs worse).
// ---------------------------------------------------------------------------
__global__ __launch_bounds__(256, 1) void plstm_persist3(
    const unsigned short* __restrict__ xf,
    const unsigned short* __restrict__ Wf,
    unsigned short* __restrict__ hb0,
    unsigned short* __restrict__ hb1,
    float* __restrict__ hplain,
    const float* __restrict__ bias,
    const float* __restrict__ tau,
    const float* __restrict__ shift,
    int* __restrict__ ctl)
{
    __shared__ unsigned short wfl[4 * KSTEPS * 64 * 8];  // 147456 B
    __shared__ float gl[32][65];                          // 8320 B
    __shared__ int protflag;

    int tid = threadIdx.x;
    int lane = tid & 63, w = tid >> 6;
    int bid = blockIdx.x;
    int mt = bid & 7, hg = bid >> 3;
    int quad = lane >> 4, l16 = lane & 15;
    int mb = w & 1;
    int n0 = (w >> 1) * 2;

    // --- XCD-uniformity handshake (one-time) ---
    int xcc = __builtin_amdgcn_s_getreg((31 << 11) | (0 << 6) | 20); // HW_REG_XCC_ID
    if (tid == 0) {
        __hip_atomic_store(&ctl[544 + bid], xcc + 1, __ATOMIC_RELAXED,
                           __HIP_MEMORY_SCOPE_AGENT);
        asm volatile("s_waitcnt vmcnt(0)" ::: "memory");
        __hip_atomic_fetch_add(&ctl[512], 1, __ATOMIC_RELAXED,
                               __HIP_MEMORY_SCOPE_AGENT);
        while (__hip_atomic_load(&ctl[512], __ATOMIC_RELAXED,
                                 __HIP_MEMORY_SCOPE_AGENT) < 256)
            __builtin_amdgcn_s_sleep(1);
    }

    // --- stage weight slice into LDS (overlaps handshake) ---
    {
        const s16x8* src = (const s16x8*)(Wf + (size_t)(hg * 4) * KSTEPS * 64 * 8);
        s16x8* dst = (s16x8*)wfl;
        #pragma unroll
        for (int i = 0; i < 36; i++)
            dst[i * 256 + tid] = src[i * 256 + tid];
    }
    __syncthreads();

    if (w == 0) {
        int pred = 1;
        if (lane < 32) {
            int v = __hip_atomic_load(&ctl[544 + mt + 8 * lane], __ATOMIC_RELAXED,
                                      __HIP_MEMORY_SCOPE_AGENT);
            pred = (v == xcc + 1);
        }
        unsigned long long bal = __ballot(pred);
        if (lane == 0) protflag = (bal == ~0ull) ? 1 : 0;
    }
    __syncthreads();
    int fast = protflag;

    // --- per-thread epilogue constants + register state (2 cells) ---
    int b_l = tid >> 3;
    int j0  = (tid & 7) * 2;
    int bG  = mt * 32 + b_l;
    int jG0 = hg * 16 + j0;
    float bi[2], bff[2], bg[2], bo[2], phs[2], itau[2];
    #pragma unroll
    for (int r = 0; r < 2; r++) {
        int jG = jG0 + r;
        bi[r] = bias[jG];        bff[r] = bias[512 + jG];
        bg[r] = bias[1024 + jG]; bo[r] = bias[1536 + jG];
        float tj = tau[jG], sj = shift[jG];
        itau[r] = 1.f / tj;                      // precise divide, once
        float ph = fmodf(-sj, tj);
        ph = (ph < 0.f) ? ph + tj : ph;
        phs[r] = ph * itau[r];                   // phi at t=0; advanced by itau/step
    }
    float creg[2] = {0.f, 0.f}, hreg[2] = {0.f, 0.f};
    size_t pub32;
    {
        int mb2 = bG >> 4, khs2 = jG0 >> 5;
        int ln  = (bG & 15) + ((jG0 >> 3) & 3) * 16;
        pub32 = ((((size_t)mb2 * KH + khs2) * 64 + ln) * 8 + (jG0 & 7)) >> 1;
    }

    int mbg = mt * 2 + mb;
    volatile int* fcv = (volatile int*)&ctl[256 + mt * 32];
    unsigned long long fca = (unsigned long long)(ctl + 256 + mt * 32);
    int* scnt = &ctl[mt * 32];

    // --- preload xf A-frags for t=0 into registers ---
    s16x8 xa[KX];
    {
        const s16x8* x0 = (const s16x8*)xf + (size_t)mbg * KX * 64;
        #pragma unroll
        for (int ks = 0; ks < KX; ks++) xa[ks] = x0[ks * 64 + lane];
    }

    for (int t = 0; t < T_STEPS; t++) {
        // ---- x phase: MFMA from register-prefetched A-frags ----
        f32x4 acc0 = {0.f, 0.f, 0.f, 0.f}, acc1 = acc0;
        #pragma unroll
        for (int ks = 0; ks < KX; ks++) {
            s16x8 b0 = *(const s16x8*)(wfl + (((n0    ) * KSTEPS + ks) * 64 + lane) * 8);
            s16x8 b1 = *(const s16x8*)(wfl + (((n0 + 1) * KSTEPS + ks) * 64 + lane) * 8);
            acc0 = __builtin_amdgcn_mfma_f32_16x16x32_bf16(xa[ks], b0, acc0, 0, 0, 0);
            acc1 = __builtin_amdgcn_mfma_f32_16x16x32_bf16(xa[ks], b1, acc1, 0, 0, 0);
        }

        // ---- group barrier wait (proven protocol) ----
        if (tid == 0) {
            if (fast) {
                int v;
                do {
                    asm volatile("buffer_inv" ::: "memory");  // drop CU L1
                    v = *fcv;                                  // plain load -> L2
                } while (v < 32 * t);
            } else {
                while (__hip_atomic_load(scnt, __ATOMIC_RELAXED,
                                         __HIP_MEMORY_SCOPE_AGENT) < 32 * t)
                    __builtin_amdgcn_s_sleep(1);
            }
        }
        __syncthreads();

        const unsigned short* hsrc = (t & 1) ? hb1 : hb0;
        unsigned short*       hdst = (t & 1) ? hb0 : hb1;

        // ---- h phase ----
        if (fast) {
            asm volatile("buffer_inv" ::: "memory");   // per-wave L1 invalidate
            const s16x8* hs = (const s16x8*)hsrc + (size_t)mbg * KH * 64;
            #pragma unroll
            for (int khs = 0; khs < KH; khs++) {
                s16x8 a  = hs[khs * 64 + lane];
                int ks = KX + khs;
                s16x8 b0 = *(const s16x8*)(wfl + (((n0    ) * KSTEPS + ks) * 64 + lane) * 8);
                s16x8 b1 = *(const s16x8*)(wfl + (((n0 + 1) * KSTEPS + ks) * 64 + lane) * 8);
                acc0 = __builtin_amdgcn_mfma_f32_16x16x32_bf16(a, b0, acc0, 0, 0, 0);
                acc1 = __builtin_amdgcn_mfma_f32_16x16x32_bf16(a, b1, acc1, 0, 0, 0);
            }
        } else {
            const unsigned long long* hq =
                (const unsigned long long*)(hsrc + ((size_t)mbg * KH * 64) * 8);
            #pragma unroll
            for (int khs = 0; khs < KH; khs++) {
                union { unsigned long long q[2]; s16x8 v; } a;
                size_t base = ((size_t)khs * 64 + lane) * 2;
                a.q[0] = __hip_atomic_load(hq + base,     __ATOMIC_RELAXED,
                                           __HIP_MEMORY_SCOPE_AGENT);
                a.q[1] = __hip_atomic_load(hq + base + 1, __ATOMIC_RELAXED,
                                           __HIP_MEMORY_SCOPE_AGENT);
                int ks = KX + khs;
                s16x8 b0 = *(const s16x8*)(wfl + (((n0    ) * KSTEPS + ks) * 64 + lane) * 8);
                s16x8 b1 = *(const s16x8*)(wfl + (((n0 + 1) * KSTEPS + ks) * 64 + lane) * 8);
                acc0 = __builtin_amdgcn_mfma_f32_16x16x32_bf16(a.v, b0, acc0, 0, 0, 0);
                acc1 = __builtin_amdgcn_mfma_f32_16x16x32_bf16(a.v, b1, acc1, 0, 0, 0);
            }
        }

        // ---- dump accs to LDS (C/D: col=lane&15, row=quad*4+reg) ----
        int colb = n0 * 16 + l16;
        int rowb = mb * 16 + quad * 4;
        #pragma unroll
        for (int r = 0; r < 4; r++) {
            gl[rowb + r][colb]      = acc0[r];
            gl[rowb + r][colb + 16] = acc1[r];
        }
        __syncthreads();

        // ---- prefetch next-step xf A-frags (flight hides under epilogue) ----
        {
            int tp = (t < T_STEPS - 1) ? t + 1 : t;      // clamp: no OOB at t=255
            const s16x8* xn = (const s16x8*)xf + ((size_t)tp * 16 + mbg) * KX * 64;
            #pragma unroll
            for (int ks = 0; ks < KX; ks++) xa[ks] = xn[ks * 64 + lane];
        }

        // ---- epilogue: activations + cell + phased gate (fast math) ----
        float hn2[2];
        #pragma unroll
        for (int r = 0; r < 2; r++) {
            int j_l = j0 + r;
            float iv = fsigmoid(gl[b_l][j_l]      + bi[r]);
            float fv = fsigmoid(gl[b_l][16 + j_l] + bff[r]);
            float gv = ftanh_f (gl[b_l][32 + j_l] + bg[r]);
            float ov = fsigmoid(gl[b_l][48 + j_l] + bo[r]);
            float ct = fv * creg[r] + iv * gv;
            float ht = ov * ftanh_f(ct);
            float ph = phs[r];
            float kg = (ph < 0.025f) ? 40.f * ph
                     : ((ph < 0.05f) ? 2.f - 40.f * ph : 0.001f * ph);
            creg[r] = kg * ct + (1.f - kg) * creg[r];
            hreg[r] = kg * ht + (1.f - kg) * hreg[r];
            hn2[r] = hreg[r];
            ph += itau[r];                         // advance phase, wrap
            phs[r] = (ph >= 1.f) ? ph - 1.f : ph;
        }
        unsigned pv = (unsigned)f2bf(hn2[0]) | ((unsigned)f2bf(hn2[1]) << 16);
        if (fast) {
            ((unsigned*)hdst)[pub32] = pv;              // write-through to L2
        } else {
            __hip_atomic_store((unsigned*)hdst + pub32, pv, __ATOMIC_RELAXED,
                               __HIP_MEMORY_SCOPE_AGENT);
        }
        if (t == T_STEPS - 1) {
            hplain[(size_t)bG * HID + jG0]     = hn2[0];
            hplain[(size_t)bG * HID + jG0 + 1] = hn2[1];
        }
        __syncthreads();   // drains vmcnt: publish visible at coherence point

        // ---- group barrier arrive (proven protocol) ----
        if (tid == 0) {
            if (fast) {
                int one = 1;
                asm volatile("global_atomic_add %0, %1, off"
                             :: "v"(fca), "v"(one) : "memory");  // L2-executed
            } else {
                __hip_atomic_fetch_add(scnt, 1, __ATOMIC_RELAXED,
                                       __HIP_MEMORY_SCOPE_AGENT);
            }
        }
    }
}

// ---------------------------------------------------------------------------
// FALLBACK persistent kernel (proven) — used when ws_size < WS_NEED.
// ---------------------------------------------------------------------------
__global__ __launch_bounds__(256, 1) void plstm_persist(
    const float* __restrict__ x,
    const unsigned short* __restrict__ Wf,
    unsigned short* __restrict__ hb0,
    unsigned short* __restrict__ hb1,
    float* __restrict__ hplain,
    const float* __restrict__ bias,
    const float* __restrict__ tau,
    const float* __restrict__ shift,
    int* __restrict__ cnt)
{
    __shared__ unsigned short wfl[4 * KSTEPS * 64 * 8];
    __shared__ float gl[32][65];

    int tid = threadIdx.x;
    int lane = tid & 63, w = tid >> 6;
    int mt = blockIdx.x & 7, hg = blockIdx.x >> 3;
    int quad = lane >> 4, l16 = lane & 15;
    int mb = w & 1;
    int n0 = (w >> 1) * 2;

    {
        const s16x8* src = (const s16x8*)(Wf + (size_t)(hg * 4) * KSTEPS * 64 * 8);
        s16x8* dst = (s16x8*)wfl;
        #pragma unroll
        for (int i = 0; i < 36; i++)
            dst[i * 256 + tid] = src[i * 256 + tid];
    }

    int b_l  = tid >> 3;
    int j_l0 = (tid & 7) * 2;
    int bG   = mt * 32 + b_l;
    int jG0  = hg * 16 + j_l0;
    float bi[2], bff[2], bg[2], bo[2], tj[2], sj[2];
    #pragma unroll
    for (int r = 0; r < 2; r++) {
        int jG = jG0 + r;
        bi[r] = bias[jG];        bff[r] = bias[512 + jG];
        bg[r] = bias[1024 + jG]; bo[r] = bias[1536 + jG];
        tj[r] = tau[jG];         sj[r] = shift[jG];
    }
    float creg[2] = {0.f, 0.f}, hreg[2] = {0.f, 0.f};
    size_t pub32;
    {
        int mb2  = bG >> 4, khs2 = jG0 >> 5;
        int ln   = (bG & 15) + ((jG0 >> 3) & 3) * 16;
        pub32 = ((((size_t)mb2 * KH + khs2) * 64 + ln) * 8 + (jG0 & 7)) >> 1;
    }
    __syncthreads();

    int rowA = mt * 32 + mb * 16 + l16;
    int mbg  = mt * 2 + mb;
    int* mycnt = cnt + mt * 32;

    for (int t = 0; t < T_STEPS; t++) {
        f32x4 acc0 = {0.f,0.f,0.f,0.f}, acc1 = acc0;
        #pragma unroll
        for (int ks = 0; ks < KX; ks++) {
            int k = ks * 32 + quad * 8;
            int p = k >> 7, f = k & 127;
            const float* sp = x + ((size_t)(rowA * 5 + p) * 256 + t) * 128 + f;
            float4 u0 = *(const float4*)sp;
            float4 u1 = *(const float4*)(sp + 4);
            s16x8 a = pack8(u0, u1);
            s16x8 b0 = *(const s16x8*)(wfl + (((n0    ) * KSTEPS + ks) * 64 + lane) * 8);
            s16x8 b1 = *(const s16x8*)(wfl + (((n0 + 1) * KSTEPS + ks) * 64 + lane) * 8);
            acc0 = __builtin_amdgcn_mfma_f32_16x16x32_bf16(a, b0, acc0, 0, 0, 0);
            acc1 = __builtin_amdgcn_mfma_f32_16x16x32_bf16(a, b1, acc1, 0, 0, 0);
        }

        if (tid == 0) {
            while (__hip_atomic_load(mycnt, __ATOMIC_RELAXED,
                                     __HIP_MEMORY_SCOPE_AGENT) < 32 * t)
                __builtin_amdgcn_s_sleep(1);
        }
        __syncthreads();

        const unsigned short* hsrc = (t & 1) ? hb1 : hb0;
        unsigned short*       hdst = (t & 1) ? hb0 : hb1;

        const unsigned long long* hq =
            (const unsigned long long*)(hsrc + ((size_t)mbg * KH * 64) * 8);
        #pragma unroll
        for (int khs = 0; khs < KH; khs++) {
            union { unsigned long long q[2]; s16x8 v; } a;
            size_t base = ((size_t)khs * 64 + lane) * 2;
            a.q[0] = __hip_atomic_load(hq + base,     __ATOMIC_RELAXED,
                                       __HIP_MEMORY_SCOPE_AGENT);
            a.q[1] = __hip_atomic_load(hq + base + 1, __ATOMIC_RELAXED,
                                       __HIP_MEMORY_SCOPE_AGENT);
            int ks = KX + khs;
            s16x8 b0 = *(const s16x8*)(wfl + (((n0    ) * KSTEPS + ks) * 64 + lane) * 8);
            s16x8 b1 = *(const s16x8*)(wfl + (((n0 + 1) * KSTEPS + ks) * 64 + lane) * 8);
            acc0 = __builtin_amdgcn_mfma_f32_16x16x32_bf16(a.v, b0, acc0, 0, 0, 0);
            acc1 = __builtin_amdgcn_mfma_f32_16x16x32_bf16(a.v, b1, acc1, 0, 0, 0);
        }

        int colb = n0 * 16 + l16;
        int rowb = mb * 16 + quad * 4;
        #pragma unroll
        for (int r = 0; r < 4; r++) {
            gl[rowb + r][colb]      = acc0[r];
            gl[rowb + r][colb + 16] = acc1[r];
        }
        __syncthreads();

        float hn2[2];
        #pragma unroll
        for (int r = 0; r < 2; r++) {
            int j_l = j_l0 + r;
            float iv = gl[b_l][j_l]      + bi[r];
            float fv = gl[b_l][16 + j_l] + bff[r];
            float gv = gl[b_l][32 + j_l] + bg[r];
            float ov = gl[b_l][48 + j_l] + bo[r];
            iv = 1.f / (1.f + expf(-iv));
            fv = 1.f / (1.f + expf(-fv));
            gv = tanhf(gv);
            ov = 1.f / (1.f + expf(-ov));
            float ct = fv * creg[r] + iv * gv;
            float ht = ov * tanhf(ct);
            float phi = fmodf((float)t - sj[r], tj[r]);
            phi = (phi < 0.f) ? phi + tj[r] : phi;
            phi /= tj[r];
            float kg = (phi < 0.025f) ? 40.f * phi
                     : ((phi < 0.05f) ? 2.f - 40.f * phi : 0.001f * phi);
            creg[r] = kg * ct + (1.f - kg) * creg[r];
            hreg[r] = kg * ht + (1.f - kg) * hreg[r];
            hn2[r] = hreg[r];
        }
        unsigned pv = (unsigned)f2bf(hn2[0]) | ((unsigned)f2bf(hn2[1]) << 16);
        __hip_atomic_store((unsigned*)hdst + pub32, pv, __ATOMIC_RELAXED,
                           __HIP_MEMORY_SCOPE_AGENT);
        if (t == T_STEPS - 1) {
            hplain[(size_t)bG * HID + jG0]     = hn2[0];
            hplain[(size_t)bG * HID + jG0 + 1] = hn2[1];
        }
        __syncthreads();

        if (tid == 0)
            __hip_atomic_fetch_add(mycnt, 1, __ATOMIC_RELAXED,
                                   __HIP_MEMORY_SCOPE_AGENT);
    }
}

// ---------------------------------------------------------------------------
// Final FC (512 -> 60) + log_softmax. One wave per batch row.
// ---------------------------------------------------------------------------
__global__ __launch_bounds__(64) void fc_kernel(
    const float* __restrict__ hplain, const float* __restrict__ fcw,
    const float* __restrict__ fcb, float* __restrict__ out)
{
    int b = blockIdx.x, lane = threadIdx.x;
    float logit = -INFINITY;
    if (lane < NCLASS) {
        float s = fcb[lane];
        const float* hp = hplain + (size_t)b * HID;
        #pragma unroll 8
        for (int k = 0; k < HID; k++)
            s += hp[k] * fcw[(size_t)k * NCLASS + lane];
        logit = s;
    }
    float m = logit;
    for (int off = 32; off > 0; off >>= 1)
        m = fmaxf(m, __shfl_xor(m, off, 64));
    float e = (lane < NCLASS) ? expf(logit - m) : 0.f;
    float se = e;
    for (int off = 32; off > 0; off >>= 1)
        se += __shfl_xor(se, off, 64);
    if (lane < NCLASS)
        out[(size_t)b * NCLASS + lane] = logit - m - logf(se);
}

extern "C" void kernel_launch(void* const* d_in, const int* in_sizes, int n_in,
                              void* d_out, int out_size, void* d_ws, size_t ws_size,
                              hipStream_t stream)
{
    const float* x     = (const float*)d_in[0];
    const float* Wx    = (const float*)d_in[1];
    const float* Wh    = (const float*)d_in[2];
    const float* bias  = (const float*)d_in[3];
    const float* tau   = (const float*)d_in[4];
    const float* shift = (const float*)d_in[5];
    const float* fcw   = (const float*)d_in[6];
    const float* fcb   = (const float*)d_in[7];
    float* out = (float*)d_out;
    char* ws = (char*)d_ws;

    int*            ctl    = (int*)ws;
    unsigned short* Wf     = (unsigned short*)(ws + WF_OFF);
    unsigned short* hb0    = (unsigned short*)(ws + HB0_OFF);
    unsigned short* hb1    = (unsigned short*)(ws + HB1_OFF);
    float*          hplain = (float*)(ws + HPL_OFF);
    unsigned short* xfb    = (unsigned short*)(ws + XF_OFF);

    hipMemsetAsync(ws, 0, 4096, stream);                 // control block
    hipMemsetAsync(ws + HB0_OFF, 0, 262144, stream);     // h0 = 0

    pack_w_kernel<<<dim3(1152), dim3(256), 0, stream>>>(Wx, Wh, Wf);

    if (ws_size >= WS_NEED) {
        xf_kernel<<<dim3(4096), dim3(256), 0, stream>>>(x, xfb);
        plstm_persist3<<<dim3(256), dim3(256), 0, stream>>>(
            xfb, Wf, hb0, hb1, hplain, bias, tau, shift, ctl);
    } else {
        plstm_persist<<<dim3(256), dim3(256), 0, stream>>>(
            x, Wf, hb0, hb1, hplain, bias, tau, shift, ctl);
    }

    fc_kernel<<<dim3(256), dim3(64), 0, stream>>>(hplain, fcw, fcb, out);
}